// Round 1
// baseline (4170.018 us; speedup 1.0000x reference)
//
#include <hip/hip_runtime.h>
#include <hip/hip_bf16.h>
#include <math.h>

#define SEQ     2048
#define NHEAD   16
#define HDIM    128
#define HIDDEN  2048
#define QKV_N   6144
#define CHUNKSZ 256
#define NCHUNK  8
#define SCALE_F 0.08838834764831845f
#define NEGBIG  -1e30f

// ---------------- C[M,N] = A[M,K] @ B[N,K]^T (both row-major along K) -------
__global__ __launch_bounds__(256) void sgemm_nt(const float* __restrict__ A,
                                                const float* __restrict__ B,
                                                float* __restrict__ C,
                                                int M, int N, int K) {
  __shared__ float As[8][128];
  __shared__ float Bs[8][128];
  const int tid = threadIdx.x;
  const int bm = blockIdx.y * 128;
  const int bn = blockIdx.x * 128;
  const int tx = tid & 15;
  const int ty = tid >> 4;
  const int lr = tid >> 1;          // 0..127: row within tile for loads
  const int lc = (tid & 1) * 4;     // 0 or 4: k-col within 8-wide K tile
  const float* Ap = A + (size_t)(bm + lr) * K + lc;
  const float* Bp = B + (size_t)(bn + lr) * K + lc;
  float acc[8][8];
#pragma unroll
  for (int i = 0; i < 8; ++i)
#pragma unroll
    for (int j = 0; j < 8; ++j) acc[i][j] = 0.f;

  for (int k0 = 0; k0 < K; k0 += 8) {
    float4 av = *(const float4*)(Ap + k0);
    float4 bv = *(const float4*)(Bp + k0);
    __syncthreads();
    As[lc + 0][lr] = av.x; As[lc + 1][lr] = av.y;
    As[lc + 2][lr] = av.z; As[lc + 3][lr] = av.w;
    Bs[lc + 0][lr] = bv.x; Bs[lc + 1][lr] = bv.y;
    Bs[lc + 2][lr] = bv.z; Bs[lc + 3][lr] = bv.w;
    __syncthreads();
#pragma unroll
    for (int kk = 0; kk < 8; ++kk) {
      float a[8], b[8];
      *(float4*)&a[0] = *(const float4*)&As[kk][ty * 8];
      *(float4*)&a[4] = *(const float4*)&As[kk][ty * 8 + 4];
      *(float4*)&b[0] = *(const float4*)&Bs[kk][tx * 8];
      *(float4*)&b[4] = *(const float4*)&Bs[kk][tx * 8 + 4];
#pragma unroll
      for (int i = 0; i < 8; ++i)
#pragma unroll
        for (int j = 0; j < 8; ++j)
          acc[i][j] = fmaf(a[i], b[j], acc[i][j]);
    }
  }
#pragma unroll
  for (int i = 0; i < 8; ++i) {
    size_t row = (size_t)(bm + ty * 8 + i);
    float4 c0 = make_float4(acc[i][0], acc[i][1], acc[i][2], acc[i][3]);
    float4 c1 = make_float4(acc[i][4], acc[i][5], acc[i][6], acc[i][7]);
    *(float4*)&C[row * N + bn + tx * 8] = c0;
    *(float4*)&C[row * N + bn + tx * 8 + 4] = c1;
  }
}

// ---------------- in-place RoPE on q and k inside qkv -----------------------
// thread = (b, s, h, j) with j in 0..63; owns elements j and j+64 of the head.
__global__ __launch_bounds__(256) void rope_inplace(float* __restrict__ qkv,
                                                    const int* __restrict__ pos) {
  int idx = blockIdx.x * 256 + threadIdx.x;     // 2*2048*16*64 = 2^22 threads
  int j = idx & 63;
  int h = (idx >> 6) & 15;
  int s = (idx >> 10) & (SEQ - 1);
  int b = idx >> 21;
  float p = (float)pos[b * SEQ + s];
  // inv = 10000^(-j/64), computed in f64 to track XLA's constant folding
  float inv = (float)exp(-(double)j * 1.4391156831212787e-1); // ln(10000)/64
  float ang = p * inv;
  float sn = sinf(ang);
  float cs = cosf(ang);
  size_t row = (size_t)(b * SEQ + s) * QKV_N;
  float* qp = qkv + row + h * HDIM;
  float x1 = qp[j], x2 = qp[j + 64];
  qp[j] = x1 * cs - x2 * sn;
  qp[j + 64] = x2 * cs + x1 * sn;
  float* kp = qkv + row + HIDDEN + h * HDIM;
  x1 = kp[j]; x2 = kp[j + 64];
  kp[j] = x1 * cs - x2 * sn;
  kp[j + 64] = x2 * cs + x1 * sn;
}

// ---------------- key_gate[b,h,n,d] = mean over chunk of roped k ------------
__global__ __launch_bounds__(128) void key_gate_k(const float* __restrict__ qkv,
                                                  float* __restrict__ kg) {
  int bhn = blockIdx.x;           // ((b*16+h)*8+n)
  int d = threadIdx.x;
  int n = bhn & 7;
  int bh = bhn >> 3;
  int b = bh >> 4, h = bh & 15;
  const float* kp = qkv + (size_t)(b * SEQ + n * CHUNKSZ) * QKV_N + HIDDEN + h * HDIM + d;
  float sum = 0.f;
  for (int i = 0; i < CHUNKSZ; ++i) sum += kp[(size_t)i * QKV_N];
  kg[(size_t)bh * NCHUNK * HDIM + n * HDIM + d] = sum * (1.f / CHUNKSZ);
}

// ---------------- gate + top-k chunk selection (one wave per (b,h,s)) -------
__global__ __launch_bounds__(256) void gate_topk(const float* __restrict__ qkv,
                                                 const float* __restrict__ kg,
                                                 unsigned char* __restrict__ msk) {
  int gw = (blockIdx.x * 256 + threadIdx.x) >> 6;   // (b*16+h)*2048 + s
  int lane = threadIdx.x & 63;
  int s = gw & (SEQ - 1);
  int bh = gw >> 11;
  int b = bh >> 4, h = bh & 15;
  int cq = s >> 8;
  const float* qp = qkv + (size_t)(b * SEQ + s) * QKV_N + h * HDIM;
  float q0 = qp[lane], q1 = qp[lane + 64];
  const float* kgp = kg + (size_t)bh * NCHUNK * HDIM;
  float g[7];
#pragma unroll
  for (int n = 0; n < 7; ++n) {
    float part = 0.f;
    if (n < cq) part = q0 * kgp[n * HDIM + lane] + q1 * kgp[n * HDIM + lane + 64];
#pragma unroll
    for (int off = 32; off > 0; off >>= 1) part += __shfl_xor(part, off);
    g[n] = part;   // full gate value on every lane (only n<cq meaningful)
  }
  unsigned m = 1u << cq;                 // self chunk always selected
  int nsel = cq < 3 ? cq : 3;            // top-3 past chunks (top-4 incl. self)
#pragma unroll
  for (int it = 0; it < 3; ++it) {
    int best = -1; float bv = 0.f;
#pragma unroll
    for (int n = 0; n < 7; ++n) {
      bool cand = (n < cq) && !((m >> n) & 1u);
      if (cand && (best < 0 || g[n] > bv)) { bv = g[n]; best = n; } // tie -> lower idx
    }
    if (it < nsel) m |= 1u << best;
  }
  if (lane == 0) msk[gw] = (unsigned char)m;
}

// ---------------- MoBA flash attention (f32 vector) -------------------------
// block = (qtile of 64 queries, h, b); 4 waves x 16 queries each.
// scores: lane = key (kl=lane&31), rep=lane>>5 picks 8-query half.
// PV:     lane = d-quad (kl), same rep/query mapping; P transposed via LDS.
__global__ __launch_bounds__(256) void moba_attn(const float* __restrict__ qkv,
                                                 const unsigned char* __restrict__ msk,
                                                 float* __restrict__ o) {
  __shared__ float Qs[64][132];
  __shared__ float Ks[32][132];
  __shared__ float Vs[32][132];
  __shared__ float Ps[4][16][36];
  __shared__ unsigned char Ms[64];
  __shared__ unsigned int bmask_sh;

  const int qt = blockIdx.x, h = blockIdx.y, b = blockIdx.z;
  const int tid = threadIdx.x;
  const int w = tid >> 6, lane = tid & 63;
  const int rep = lane >> 5, kl = lane & 31;
  const int bh = b * NHEAD + h;
  const int q0g = qt * 64;
  const int cq = q0g >> 8;

  { // stage Q tile 64x128
    int r = tid >> 2;
    int cbase = (tid & 3) * 32;
    const float* src = qkv + (size_t)(b * SEQ + q0g + r) * QKV_N + h * HDIM + cbase;
#pragma unroll
    for (int i = 0; i < 8; ++i)
      *(float4*)&Qs[r][cbase + i * 4] = *(const float4*)(src + i * 4);
  }
  if (tid < 64) Ms[tid] = msk[(size_t)bh * SEQ + q0g + tid];
  __syncthreads();
  if (tid == 0) {
    unsigned mm = 0;
    for (int i = 0; i < 64; ++i) mm |= Ms[i];
    bmask_sh = mm;
  }
  __syncthreads();
  const unsigned bmask = bmask_sh;

  unsigned char mrow[8];
  int srow[8];
#pragma unroll
  for (int j = 0; j < 8; ++j) {
    int ql = w * 16 + rep * 8 + j;
    mrow[j] = Ms[ql];
    srow[j] = q0g + ql;
  }
  float m_run[8], l_run[8], Oa[8][4];
#pragma unroll
  for (int j = 0; j < 8; ++j) {
    m_run[j] = NEGBIG; l_run[j] = 0.f;
#pragma unroll
    for (int i = 0; i < 4; ++i) Oa[j][i] = 0.f;
  }
  const int qb = w * 16 + rep * 8;

  for (int n = 0; n <= cq; ++n) {
    if (!((bmask >> n) & 1u)) continue;              // block-uniform skip
    const int nk = (n == cq) ? ((qt & 3) * 64 + 64) : CHUNKSZ;
    for (int kt0 = 0; kt0 < nk; kt0 += 32) {
      __syncthreads();                                // protect prior Ks/Vs reads
      { // stage K,V subtile 32x128
        int r = tid >> 3;
        int c = (tid & 7) * 16;
        const float* ksrc = qkv + (size_t)(b * SEQ + n * CHUNKSZ + kt0 + r) * QKV_N
                            + HIDDEN + h * HDIM + c;
        const float* vsrc = ksrc + HIDDEN;
#pragma unroll
        for (int i = 0; i < 4; ++i) {
          *(float4*)&Ks[r][c + i * 4] = *(const float4*)(ksrc + i * 4);
          *(float4*)&Vs[r][c + i * 4] = *(const float4*)(vsrc + i * 4);
        }
      }
      __syncthreads();

      // ---- scores: 16 queries x 32 keys per wave ----
      float sc[8];
#pragma unroll
      for (int j = 0; j < 8; ++j) sc[j] = 0.f;
#pragma unroll 4
      for (int d0 = 0; d0 < HDIM; d0 += 4) {
        float4 kv = *(const float4*)&Ks[kl][d0];
#pragma unroll
        for (int j = 0; j < 8; ++j) {
          float4 qv = *(const float4*)&Qs[qb + j][d0];   // broadcast read
          sc[j] += qv.x * kv.x + qv.y * kv.y + qv.z * kv.z + qv.w * kv.w;
        }
      }
      const int tglob = n * CHUNKSZ + kt0 + kl;

      // ---- online softmax update ----
      float p[8];
#pragma unroll
      for (int j = 0; j < 8; ++j) {
        float sv = sc[j] * SCALE_F;
        bool ok = ((mrow[j] >> n) & 1) && (tglob <= srow[j]);
        sv = ok ? sv : NEGBIG;
        float mx = sv;
        mx = fmaxf(mx, __shfl_xor(mx, 1));
        mx = fmaxf(mx, __shfl_xor(mx, 2));
        mx = fmaxf(mx, __shfl_xor(mx, 4));
        mx = fmaxf(mx, __shfl_xor(mx, 8));
        mx = fmaxf(mx, __shfl_xor(mx, 16));
        float mnew = fmaxf(m_run[j], mx);
        float alpha = __expf(m_run[j] - mnew);
        float pp = __expf(sv - mnew);
        float ps = pp;
        ps += __shfl_xor(ps, 1);
        ps += __shfl_xor(ps, 2);
        ps += __shfl_xor(ps, 4);
        ps += __shfl_xor(ps, 8);
        ps += __shfl_xor(ps, 16);
        l_run[j] = l_run[j] * alpha + ps;
        m_run[j] = mnew;
        p[j] = pp;
#pragma unroll
        for (int i = 0; i < 4; ++i) Oa[j][i] *= alpha;
      }
      // transpose P through LDS (per-wave slab)
#pragma unroll
      for (int j = 0; j < 8; ++j) Ps[w][rep * 8 + j][kl] = p[j];
      __syncthreads();

      // ---- PV: lane = d-quad ----
#pragma unroll 4
      for (int kk = 0; kk < 32; ++kk) {
        float4 vv = *(const float4*)&Vs[kk][kl * 4];
#pragma unroll
        for (int j = 0; j < 8; ++j) {
          float pj = Ps[w][rep * 8 + j][kk];            // broadcast read
          Oa[j][0] = fmaf(pj, vv.x, Oa[j][0]);
          Oa[j][1] = fmaf(pj, vv.y, Oa[j][1]);
          Oa[j][2] = fmaf(pj, vv.z, Oa[j][2]);
          Oa[j][3] = fmaf(pj, vv.w, Oa[j][3]);
        }
      }
    }
  }
  // epilogue: normalize and write o[(b,s),(h,d)]
#pragma unroll
  for (int j = 0; j < 8; ++j) {
    float inv = 1.f / l_run[j];
    float4 t = make_float4(Oa[j][0] * inv, Oa[j][1] * inv,
                           Oa[j][2] * inv, Oa[j][3] * inv);
    *(float4*)&o[(size_t)(b * SEQ + srow[j]) * HIDDEN + h * HDIM + kl * 4] = t;
  }
}

// ---------------------------------------------------------------------------
extern "C" void kernel_launch(void* const* d_in, const int* in_sizes, int n_in,
                              void* d_out, int out_size, void* d_ws, size_t ws_size,
                              hipStream_t stream) {
  const float* hs    = (const float*)d_in[0];   // (2,2048,2048) f32
  const int*   pos   = (const int*)d_in[1];     // (2,2048) i32
  const float* w_qkv = (const float*)d_in[2];   // (6144,2048) f32
  const float* w_o   = (const float*)d_in[3];   // (2048,2048) f32
  float* out = (float*)d_out;                   // (2,2048,2048) f32

  char* ws = (char*)d_ws;
  float* qkv = (float*)ws;                                        // 96 MB
  float* o   = (float*)(ws + (size_t)4096 * QKV_N * 4);           // 32 MB
  float* kg  = (float*)(ws + (size_t)4096 * QKV_N * 4
                           + (size_t)4096 * HIDDEN * 4);          // 128 KB
  unsigned char* msk = (unsigned char*)(kg + 2 * NHEAD * NCHUNK * HDIM);

  // 1) QKV projection
  sgemm_nt<<<dim3(QKV_N / 128, 4096 / 128), 256, 0, stream>>>(hs, w_qkv, qkv,
                                                              4096, QKV_N, HIDDEN);
  // 2) RoPE in place on q,k
  rope_inplace<<<(2 * SEQ * NHEAD * 64) / 256, 256, 0, stream>>>(qkv, pos);
  // 3) chunk key means
  key_gate_k<<<2 * NHEAD * NCHUNK, 128, 0, stream>>>(qkv, kg);
  // 4) gate + top-k selection mask
  gate_topk<<<(2 * NHEAD * SEQ * 64) / 256, 256, 0, stream>>>(qkv, kg, msk);
  // 5) MoBA attention
  moba_attn<<<dim3(SEQ / 64, NHEAD, 2), 256, 0, stream>>>(qkv, msk, o);
  // 6) output projection
  sgemm_nt<<<dim3(HIDDEN / 128, 4096 / 128), 256, 0, stream>>>(o, w_o, out,
                                                               4096, HIDDEN, HIDDEN);
}

// Round 2
// 2127.702 us; speedup vs baseline: 1.9599x; 1.9599x over previous
//
#include <hip/hip_runtime.h>
#include <hip/hip_bf16.h>
#include <math.h>
#include <string.h>

#define SEQ     2048
#define NHEAD   16
#define HDIM    128
#define HIDDEN  2048
#define QKV_N   6144
#define CHUNKSZ 256
#define NCHUNK  8
#define SCALE_F 0.08838834764831845f
#define NEGBIG  -1e30f

typedef unsigned short u16;
typedef unsigned int   u32;
typedef __attribute__((ext_vector_type(8))) short s16x8;
typedef __attribute__((ext_vector_type(4))) float f32x4;

__device__ __forceinline__ u16 f2bf(float x) {
  __hip_bfloat16 h = __float2bfloat16(x);
  u16 r; memcpy(&r, &h, 2); return r;
}
__device__ __forceinline__ float bf2f(u16 u) {
  u32 b = (u32)u << 16; float f; memcpy(&f, &b, 4); return f;
}

// ---------------- C[M,N] = A[M,K] @ B[N,K]^T (f32, unchanged) ---------------
__global__ __launch_bounds__(256) void sgemm_nt(const float* __restrict__ A,
                                                const float* __restrict__ B,
                                                float* __restrict__ C,
                                                int M, int N, int K) {
  __shared__ float As[8][128];
  __shared__ float Bs[8][128];
  const int tid = threadIdx.x;
  const int bm = blockIdx.y * 128;
  const int bn = blockIdx.x * 128;
  const int tx = tid & 15;
  const int ty = tid >> 4;
  const int lr = tid >> 1;
  const int lc = (tid & 1) * 4;
  const float* Ap = A + (size_t)(bm + lr) * K + lc;
  const float* Bp = B + (size_t)(bn + lr) * K + lc;
  float acc[8][8];
#pragma unroll
  for (int i = 0; i < 8; ++i)
#pragma unroll
    for (int j = 0; j < 8; ++j) acc[i][j] = 0.f;

  for (int k0 = 0; k0 < K; k0 += 8) {
    float4 av = *(const float4*)(Ap + k0);
    float4 bv = *(const float4*)(Bp + k0);
    __syncthreads();
    As[lc + 0][lr] = av.x; As[lc + 1][lr] = av.y;
    As[lc + 2][lr] = av.z; As[lc + 3][lr] = av.w;
    Bs[lc + 0][lr] = bv.x; Bs[lc + 1][lr] = bv.y;
    Bs[lc + 2][lr] = bv.z; Bs[lc + 3][lr] = bv.w;
    __syncthreads();
#pragma unroll
    for (int kk = 0; kk < 8; ++kk) {
      float a[8], b[8];
      *(float4*)&a[0] = *(const float4*)&As[kk][ty * 8];
      *(float4*)&a[4] = *(const float4*)&As[kk][ty * 8 + 4];
      *(float4*)&b[0] = *(const float4*)&Bs[kk][tx * 8];
      *(float4*)&b[4] = *(const float4*)&Bs[kk][tx * 8 + 4];
#pragma unroll
      for (int i = 0; i < 8; ++i)
#pragma unroll
        for (int j = 0; j < 8; ++j)
          acc[i][j] = fmaf(a[i], b[j], acc[i][j]);
    }
  }
#pragma unroll
  for (int i = 0; i < 8; ++i) {
    size_t row = (size_t)(bm + ty * 8 + i);
    float4 c0 = make_float4(acc[i][0], acc[i][1], acc[i][2], acc[i][3]);
    float4 c1 = make_float4(acc[i][4], acc[i][5], acc[i][6], acc[i][7]);
    *(float4*)&C[row * N + bn + tx * 8] = c0;
    *(float4*)&C[row * N + bn + tx * 8 + 4] = c1;
  }
}

// ---------------- in-place RoPE (unchanged) ---------------------------------
__global__ __launch_bounds__(256) void rope_inplace(float* __restrict__ qkv,
                                                    const int* __restrict__ pos) {
  int idx = blockIdx.x * 256 + threadIdx.x;
  int j = idx & 63;
  int h = (idx >> 6) & 15;
  int s = (idx >> 10) & (SEQ - 1);
  int b = idx >> 21;
  float p = (float)pos[b * SEQ + s];
  float inv = (float)exp(-(double)j * 1.4391156831212787e-1);
  float ang = p * inv;
  float sn = sinf(ang);
  float cs = cosf(ang);
  size_t row = (size_t)(b * SEQ + s) * QKV_N;
  float* qp = qkv + row + h * HDIM;
  float x1 = qp[j], x2 = qp[j + 64];
  qp[j] = x1 * cs - x2 * sn;
  qp[j + 64] = x2 * cs + x1 * sn;
  float* kp = qkv + row + HIDDEN + h * HDIM;
  x1 = kp[j]; x2 = kp[j + 64];
  kp[j] = x1 * cs - x2 * sn;
  kp[j + 64] = x2 * cs + x1 * sn;
}

// ---------------- key_gate (unchanged, f32) ---------------------------------
__global__ __launch_bounds__(128) void key_gate_k(const float* __restrict__ qkv,
                                                  float* __restrict__ kg) {
  int bhn = blockIdx.x;
  int d = threadIdx.x;
  int n = bhn & 7;
  int bh = bhn >> 3;
  int b = bh >> 4, h = bh & 15;
  const float* kp = qkv + (size_t)(b * SEQ + n * CHUNKSZ) * QKV_N + HIDDEN + h * HDIM + d;
  float sum = 0.f;
  for (int i = 0; i < CHUNKSZ; ++i) sum += kp[(size_t)i * QKV_N];
  kg[(size_t)bh * NCHUNK * HDIM + n * HDIM + d] = sum * (1.f / CHUNKSZ);
}

// ---------------- gate + top-k (unchanged, f32 — precision-critical) --------
__global__ __launch_bounds__(256) void gate_topk(const float* __restrict__ qkv,
                                                 const float* __restrict__ kg,
                                                 unsigned char* __restrict__ msk) {
  int gw = (blockIdx.x * 256 + threadIdx.x) >> 6;
  int lane = threadIdx.x & 63;
  int s = gw & (SEQ - 1);
  int bh = gw >> 11;
  int b = bh >> 4, h = bh & 15;
  int cq = s >> 8;
  const float* qp = qkv + (size_t)(b * SEQ + s) * QKV_N + h * HDIM;
  float q0 = qp[lane], q1 = qp[lane + 64];
  const float* kgp = kg + (size_t)bh * NCHUNK * HDIM;
  float g[7];
#pragma unroll
  for (int n = 0; n < 7; ++n) {
    float part = 0.f;
    if (n < cq) part = q0 * kgp[n * HDIM + lane] + q1 * kgp[n * HDIM + lane + 64];
#pragma unroll
    for (int off = 32; off > 0; off >>= 1) part += __shfl_xor(part, off);
    g[n] = part;
  }
  unsigned m = 1u << cq;
  int nsel = cq < 3 ? cq : 3;
#pragma unroll
  for (int it = 0; it < 3; ++it) {
    int best = -1; float bv = 0.f;
#pragma unroll
    for (int n = 0; n < 7; ++n) {
      bool cand = (n < cq) && !((m >> n) & 1u);
      if (cand && (best < 0 || g[n] > bv)) { bv = g[n]; best = n; }
    }
    if (it < nsel) m |= 1u << best;
  }
  if (lane == 0) msk[gw] = (unsigned char)m;
}

// ---------------- prep: K -> frag-linear bf16 hi/lo -------------------------
// layout elem idx = (((bh*128 + kt)*4 + ds)*64 + lane)*8 + j
// lane holds K[kt*16 + (lane&15)][ds*32 + (lane>>4)*8 + j]   (B-frag for QK^T)
__global__ __launch_bounds__(256) void prep_k(const float* __restrict__ qkv,
                                              u16* __restrict__ khi,
                                              u16* __restrict__ klo) {
  int idx = blockIdx.x * 256 + threadIdx.x;      // 2^20 threads
  int lane = idx & 63;
  int ds = (idx >> 6) & 3;
  int kt = (idx >> 8) & 127;
  int bh = idx >> 15;
  int b = bh >> 4, h = bh & 15;
  int s = kt * 16 + (lane & 15);
  int d = ds * 32 + (lane >> 4) * 8;
  const float* src = qkv + (size_t)(b * SEQ + s) * QKV_N + HIDDEN + h * HDIM + d;
  float4 a = *(const float4*)src;
  float4 c = *(const float4*)(src + 4);
  float xs[8] = {a.x, a.y, a.z, a.w, c.x, c.y, c.z, c.w};
  s16x8 hi, lo;
#pragma unroll
  for (int j = 0; j < 8; ++j) {
    u16 hb = f2bf(xs[j]);
    hi[j] = (short)hb;
    lo[j] = (short)f2bf(xs[j] - bf2f(hb));
  }
  size_t dst = (size_t)idx * 8;
  *(s16x8*)&khi[dst] = hi;
  *(s16x8*)&klo[dst] = lo;
}

// ---------------- prep: V^T -> frag-linear bf16 hi/lo -----------------------
// layout elem idx = (((bh*8 + dt)*64 + ts)*64 + lane)*8 + j
// lane holds V[ts*32 + (lane>>4)*8 + j][dt*16 + (lane&15)]   (B-frag for PV)
__global__ __launch_bounds__(256) void prep_v(const float* __restrict__ qkv,
                                              u16* __restrict__ vhi,
                                              u16* __restrict__ vlo) {
  int idx = blockIdx.x * 256 + threadIdx.x;      // 2^20 threads
  int lane = idx & 63;
  int ts = (idx >> 6) & 63;
  int dt = (idx >> 12) & 7;
  int bh = idx >> 15;
  int b = bh >> 4, h = bh & 15;
  int t = ts * 32 + (lane >> 4) * 8;
  int d = dt * 16 + (lane & 15);
  const float* src = qkv + (size_t)(b * SEQ + t) * QKV_N + 2 * HIDDEN + h * HDIM + d;
  s16x8 hi, lo;
#pragma unroll
  for (int j = 0; j < 8; ++j) {
    float x = src[(size_t)j * QKV_N];
    u16 hb = f2bf(x);
    hi[j] = (short)hb;
    lo[j] = (short)f2bf(x - bf2f(hb));
  }
  size_t dst = (size_t)idx * 8;
  *(s16x8*)&vhi[dst] = hi;
  *(s16x8*)&vlo[dst] = lo;
}

// ---------------- MoBA flash attention: split-bf16 MFMA ---------------------
// block = 64 queries (qt), 4 waves x 16 q. 32-key subtiles staged in LDS.
// QK^T: A=Q (regs), B=K (LDS frag-linear). C: col=key=l&15, row=q=(l>>4)*4+r.
// PV:   A=P (LDS bounce), B=V^T.        C: col=d  =l&15, row=q=(l>>4)*4+r.
#define PSTRIDE 40   // u16 elems per P row: 80 B, 16B-aligned, bank-optimal
__global__ __launch_bounds__(256) void moba_attn_mfma(
    const float* __restrict__ qkv,
    const u16* __restrict__ khi, const u16* __restrict__ klo,
    const u16* __restrict__ vhi, const u16* __restrict__ vlo,
    const unsigned char* __restrict__ msk, float* __restrict__ o) {
  __shared__ u16 KHI[4096], KLO[4096];        // [2kt][4ds][64 lane][8]
  __shared__ u16 VHI[4096], VLO[4096];        // [8dt][64 lane][8]
  __shared__ u16 PHI[4][16 * PSTRIDE], PLO[4][16 * PSTRIDE];
  __shared__ unsigned char Ms[64];
  __shared__ unsigned bm_sh;

  const int qt = blockIdx.x, h = blockIdx.y, b = blockIdx.z;
  const int tid = threadIdx.x;
  const int w = tid >> 6, lane = tid & 63;
  const int lr = lane & 15, lg = lane >> 4;
  const int bh = b * NHEAD + h;
  const int q0g = qt * 64;
  const int q0w = q0g + w * 16;
  const int cq = qt >> 2;

  if (tid < 64) Ms[tid] = msk[(size_t)bh * SEQ + q0g + tid];
  __syncthreads();
  if (tid == 0) {
    unsigned m = 0;
    for (int i = 0; i < 64; ++i) m |= Ms[i];
    bm_sh = m;
  }

  // Q fragments (A-operand): lane holds Q[q0w + lr][ds*32 + lg*8 .. +7]
  s16x8 qh[4], ql[4];
  {
    const float* qp = qkv + (size_t)(b * SEQ + q0w + lr) * QKV_N + h * HDIM + lg * 8;
#pragma unroll
    for (int ds = 0; ds < 4; ++ds) {
      float4 a = *(const float4*)(qp + ds * 32);
      float4 c = *(const float4*)(qp + ds * 32 + 4);
      float xs[8] = {a.x, a.y, a.z, a.w, c.x, c.y, c.z, c.w};
      s16x8 hi, lo;
#pragma unroll
      for (int j = 0; j < 8; ++j) {
        u16 hb = f2bf(xs[j]);
        hi[j] = (short)hb;
        lo[j] = (short)f2bf(xs[j] - bf2f(hb));
      }
      qh[ds] = hi; ql[ds] = lo;
    }
  }
  __syncthreads();
  const unsigned bmask = bm_sh;

  int qrow[4]; unsigned char rowm[4];
#pragma unroll
  for (int r = 0; r < 4; ++r) {
    qrow[r] = q0w + lg * 4 + r;
    rowm[r] = Ms[w * 16 + lg * 4 + r];
  }

  float m_run[4], l_run[4];
  f32x4 Oacc[8];
#pragma unroll
  for (int r = 0; r < 4; ++r) { m_run[r] = NEGBIG; l_run[r] = 0.f; }
#pragma unroll
  for (int dt = 0; dt < 8; ++dt) Oacc[dt] = (f32x4){0.f, 0.f, 0.f, 0.f};

  for (int n = 0; n <= cq; ++n) {
    if (!((bmask >> n) & 1u)) continue;
    const int nk = (n == cq) ? ((qt & 3) * 64 + 64) : CHUNKSZ;
    for (int t0 = n * CHUNKSZ; t0 < n * CHUNKSZ + nk; t0 += 32) {
      __syncthreads();   // all waves done reading previous subtile
      // ---- stage 32 keys: wave0->KHI, 1->KLO, 2->VHI, 3->VLO --------------
      if (w < 2) {
        const u16* src = (w == 0 ? khi : klo) +
                         ((size_t)bh * 128 + (t0 >> 4)) * 2048 + lane * 8;
        u16* dst = (w == 0 ? KHI : KLO);
#pragma unroll
        for (int i = 0; i < 8; ++i)
          *(s16x8*)&dst[i * 512 + lane * 8] = *(const s16x8*)(src + i * 512);
      } else {
        const u16* src = (w == 2 ? vhi : vlo) +
                         ((size_t)bh * 8 * 64 + (t0 >> 5)) * 512 + lane * 8;
        u16* dst = (w == 2 ? VHI : VLO);
#pragma unroll
        for (int dt = 0; dt < 8; ++dt)
          *(s16x8*)&dst[dt * 512 + lane * 8] = *(const s16x8*)(src + (size_t)dt * 32768);
      }
      __syncthreads();

      // ---- QK^T: 16 q x 32 keys, split-bf16 (3 MFMA per d-step) -----------
      f32x4 acc[2];
      acc[0] = (f32x4){0.f, 0.f, 0.f, 0.f};
      acc[1] = (f32x4){0.f, 0.f, 0.f, 0.f};
#pragma unroll
      for (int kt = 0; kt < 2; ++kt)
#pragma unroll
        for (int ds = 0; ds < 4; ++ds) {
          s16x8 bhf = *(const s16x8*)&KHI[(kt * 4 + ds) * 512 + lane * 8];
          s16x8 blf = *(const s16x8*)&KLO[(kt * 4 + ds) * 512 + lane * 8];
          acc[kt] = __builtin_amdgcn_mfma_f32_16x16x32_bf16(qh[ds], bhf, acc[kt], 0, 0, 0);
          acc[kt] = __builtin_amdgcn_mfma_f32_16x16x32_bf16(ql[ds], bhf, acc[kt], 0, 0, 0);
          acc[kt] = __builtin_amdgcn_mfma_f32_16x16x32_bf16(qh[ds], blf, acc[kt], 0, 0, 0);
        }

      // ---- online softmax over these 32 keys ------------------------------
      const int tg0 = t0 + lr, tg1 = t0 + 16 + lr;
      float alpha[4], p0v[4], p1v[4];
#pragma unroll
      for (int r = 0; r < 4; ++r) {
        bool okm = (rowm[r] >> n) & 1;
        float a0 = (okm && tg0 <= qrow[r]) ? acc[0][r] * SCALE_F : NEGBIG;
        float a1 = (okm && tg1 <= qrow[r]) ? acc[1][r] * SCALE_F : NEGBIG;
        float mx = fmaxf(a0, a1);
        mx = fmaxf(mx, __shfl_xor(mx, 1));
        mx = fmaxf(mx, __shfl_xor(mx, 2));
        mx = fmaxf(mx, __shfl_xor(mx, 4));
        mx = fmaxf(mx, __shfl_xor(mx, 8));
        float mnew = fmaxf(m_run[r], mx);
        float al = __expf(m_run[r] - mnew);
        float p0 = __expf(a0 - mnew);
        float p1 = __expf(a1 - mnew);
        float ps = p0 + p1;
        ps += __shfl_xor(ps, 1);
        ps += __shfl_xor(ps, 2);
        ps += __shfl_xor(ps, 4);
        ps += __shfl_xor(ps, 8);
        l_run[r] = l_run[r] * al + ps;
        m_run[r] = mnew;
        alpha[r] = al; p0v[r] = p0; p1v[r] = p1;
      }
      f32x4 av = {alpha[0], alpha[1], alpha[2], alpha[3]};
#pragma unroll
      for (int dt = 0; dt < 8; ++dt) Oacc[dt] *= av;

      // ---- P -> wave-private LDS slab (hi/lo), then PV --------------------
#pragma unroll
      for (int r = 0; r < 4; ++r) {
        int row = lg * 4 + r;
        u16 h0 = f2bf(p0v[r]);
        u16 h1 = f2bf(p1v[r]);
        PHI[w][row * PSTRIDE + lr]      = h0;
        PHI[w][row * PSTRIDE + 16 + lr] = h1;
        PLO[w][row * PSTRIDE + lr]      = f2bf(p0v[r] - bf2f(h0));
        PLO[w][row * PSTRIDE + 16 + lr] = f2bf(p1v[r] - bf2f(h1));
      }
      s16x8 pah = *(const s16x8*)&PHI[w][lr * PSTRIDE + lg * 8];
      s16x8 pal = *(const s16x8*)&PLO[w][lr * PSTRIDE + lg * 8];
#pragma unroll
      for (int dt = 0; dt < 8; ++dt) {
        s16x8 vbh = *(const s16x8*)&VHI[dt * 512 + lane * 8];
        s16x8 vbl = *(const s16x8*)&VLO[dt * 512 + lane * 8];
        Oacc[dt] = __builtin_amdgcn_mfma_f32_16x16x32_bf16(pah, vbh, Oacc[dt], 0, 0, 0);
        Oacc[dt] = __builtin_amdgcn_mfma_f32_16x16x32_bf16(pal, vbh, Oacc[dt], 0, 0, 0);
        Oacc[dt] = __builtin_amdgcn_mfma_f32_16x16x32_bf16(pah, vbl, Oacc[dt], 0, 0, 0);
      }
    }
  }

  // ---- epilogue: normalize, write o[(b,s)][h*128+d] -----------------------
  float inv[4];
#pragma unroll
  for (int r = 0; r < 4; ++r) inv[r] = 1.f / l_run[r];
#pragma unroll
  for (int dt = 0; dt < 8; ++dt)
#pragma unroll
    for (int r = 0; r < 4; ++r)
      o[(size_t)(b * SEQ + qrow[r]) * HIDDEN + h * HDIM + dt * 16 + lr] =
          Oacc[dt][r] * inv[r];
}

// ---------------------------------------------------------------------------
extern "C" void kernel_launch(void* const* d_in, const int* in_sizes, int n_in,
                              void* d_out, int out_size, void* d_ws, size_t ws_size,
                              hipStream_t stream) {
  const float* hs    = (const float*)d_in[0];
  const int*   pos   = (const int*)d_in[1];
  const float* w_qkv = (const float*)d_in[2];
  const float* w_o   = (const float*)d_in[3];
  float* out = (float*)d_out;

  char* ws = (char*)d_ws;
  float* qkv = (float*)ws;                                   // 96 MB
  size_t off = (size_t)4096 * QKV_N * 4;
  float* o = (float*)(ws + off);           off += (size_t)4096 * HIDDEN * 4;   // 32 MB
  u16* khi = (u16*)(ws + off);             off += (size_t)8388608 * 2;         // 16 MB
  u16* klo = (u16*)(ws + off);             off += (size_t)8388608 * 2;
  u16* vhi = (u16*)(ws + off);             off += (size_t)8388608 * 2;
  u16* vlo = (u16*)(ws + off);             off += (size_t)8388608 * 2;
  float* kg = (float*)(ws + off);          off += (size_t)2 * NHEAD * NCHUNK * HDIM * 4;
  unsigned char* msk = (unsigned char*)(ws + off);

  // 1) QKV projection (f32)
  sgemm_nt<<<dim3(QKV_N / 128, 4096 / 128), 256, 0, stream>>>(hs, w_qkv, qkv,
                                                              4096, QKV_N, HIDDEN);
  // 2) RoPE in place
  rope_inplace<<<(2 * SEQ * NHEAD * 64) / 256, 256, 0, stream>>>(qkv, pos);
  // 3) chunk key means (f32)
  key_gate_k<<<2 * NHEAD * NCHUNK, 128, 0, stream>>>(qkv, kg);
  // 4) gate + top-k mask (f32)
  gate_topk<<<(2 * NHEAD * SEQ * 64) / 256, 256, 0, stream>>>(qkv, kg, msk);
  // 5) K/V -> frag-linear bf16 hi/lo
  prep_k<<<4096, 256, 0, stream>>>(qkv, khi, klo);
  prep_v<<<4096, 256, 0, stream>>>(qkv, vhi, vlo);
  // 6) MFMA attention
  moba_attn_mfma<<<dim3(SEQ / 64, NHEAD, 2), 256, 0, stream>>>(qkv, khi, klo,
                                                               vhi, vlo, msk, o);
  // 7) output projection (f32)
  sgemm_nt<<<dim3(HIDDEN / 128, 4096 / 128), 256, 0, stream>>>(o, w_o, out,
                                                               4096, HIDDEN, HIDDEN);
}

// Round 6
// 972.647 us; speedup vs baseline: 4.2873x; 2.1875x over previous
//
#include <hip/hip_runtime.h>
#include <hip/hip_bf16.h>
#include <math.h>
#include <string.h>

#define SEQ     2048
#define NHEAD   16
#define HDIM    128
#define HIDDEN  2048
#define QKV_N   6144
#define CHUNKSZ 256
#define NCHUNK  8
#define SCALE_F 0.08838834764831845f
#define NEGBIG  -1e30f

typedef unsigned short u16;
typedef unsigned int   u32;
typedef _Float16       f16;
typedef __attribute__((ext_vector_type(8))) short    s16x8;
typedef __attribute__((ext_vector_type(8))) _Float16 f16x8;
typedef __attribute__((ext_vector_type(4))) float    f32x4;

__device__ __forceinline__ u16 f2bf(float x) {
  __hip_bfloat16 h = __float2bfloat16(x);
  u16 r; memcpy(&r, &h, 2); return r;
}
__device__ __forceinline__ float bf2f(u16 u) {
  u32 b = (u32)u << 16; float f; memcpy(&f, &b, 4); return f;
}

// ---------------- prep: f32 row-major [R][2048] -> frag-linear fp16 hi/lo ---
// chunk (mt, ks): lane l holds X[mt*16 + (l&15)][ks*32 + (l>>4)*8 + j], j=0..7
// flat elem = ((mt*64 + ks)*64 + l)*8 + j.  lo is scaled by 2^11 (denorm-safe).
__global__ __launch_bounds__(256) void prep_fl(const float* __restrict__ src,
                                               f16* __restrict__ hi,
                                               f16* __restrict__ lo) {
  int idx = blockIdx.x * 256 + threadIdx.x;
  int l  = idx & 63;
  int ks = (idx >> 6) & 63;
  int mt = idx >> 12;
  const float* sp = src + (size_t)(mt * 16 + (l & 15)) * 2048 + ks * 32 + (l >> 4) * 8;
  float4 a = *(const float4*)sp;
  float4 b = *(const float4*)(sp + 4);
  float xs[8] = {a.x, a.y, a.z, a.w, b.x, b.y, b.z, b.w};
  f16x8 hv, lv;
#pragma unroll
  for (int j = 0; j < 8; ++j) {
    _Float16 h = (_Float16)xs[j];
    hv[j] = h;
    lv[j] = (_Float16)((xs[j] - (float)h) * 2048.0f);
  }
  size_t d = (size_t)idx * 8;
  *(f16x8*)&hi[d] = hv;
  *(f16x8*)&lo[d] = lv;
}

// ---------------- split-fp16 MFMA GEMM: C[M,N] = A[M,K] @ B[N,K]^T ----------
// A,B in frag-linear fp16 hi/lo (K=2048, KS=64). 128x128 tile, BK=32,
// 4 waves (2x2 quadrants of 64x64), 2-barrier loop, REG-STAGED LDS writes
// (ds_write_b128 pattern proven in round-2 moba kernel; no global_load_lds).
__global__ __launch_bounds__(256, 2) void gemm_fl(
    const f16* __restrict__ Ah, const f16* __restrict__ Al,
    const f16* __restrict__ Bh, const f16* __restrict__ Bl,
    float* __restrict__ C, int ldC, int coff) {
  __shared__ __align__(16) f16 sA[2][8][512];
  __shared__ __align__(16) f16 sB[2][8][512];
  const int tid = threadIdx.x;
  const int w = tid >> 6, lane = tid & 63;
  const int wr = w >> 1, wc = w & 1;
  const int lr = lane & 15, lg = lane >> 4;
  const int bm8 = blockIdx.y * 8;
  const int bn8 = blockIdx.x * 8;

  // staging role: wave 0 -> A-hi, 1 -> A-lo, 2 -> B-hi, 3 -> B-lo (8 chunks each)
  const f16* gmat = (w == 0) ? Ah : (w == 1) ? Al : (w == 2) ? Bh : Bl;
  const int  base8 = (w < 2) ? bm8 : bn8;
  f16* lmat = (w == 0) ? &sA[0][0][0] : (w == 1) ? &sA[1][0][0]
            : (w == 2) ? &sB[0][0][0] : &sB[1][0][0];
  const f16* gw = gmat + (size_t)lane * 8;
  f16* lw = lmat + lane * 8;

  f32x4 accH[4][4], accX[4][4];
#pragma unroll
  for (int i = 0; i < 4; ++i)
#pragma unroll
    for (int j = 0; j < 4; ++j) {
      accH[i][j] = (f32x4){0.f, 0.f, 0.f, 0.f};
      accX[i][j] = (f32x4){0.f, 0.f, 0.f, 0.f};
    }

  for (int ks = 0; ks < 64; ++ks) {
    // issue all 8 global loads first (independent), then LDS writes
    f16x8 stg[8];
#pragma unroll
    for (int i = 0; i < 8; ++i)
      stg[i] = *(const f16x8*)(gw + (((size_t)(base8 + i) * 64 + ks) << 9));
    __syncthreads();                          // readers done with LDS buffer
#pragma unroll
    for (int i = 0; i < 8; ++i)
      *(f16x8*)(lw + (i << 9)) = stg[i];
    __syncthreads();                          // staging complete

    f16x8 ah[4], al[4], bh[4], bl[4];
#pragma unroll
    for (int i = 0; i < 4; ++i) {
      ah[i] = *(const f16x8*)&sA[0][wr * 4 + i][lane * 8];
      al[i] = *(const f16x8*)&sA[1][wr * 4 + i][lane * 8];
      bh[i] = *(const f16x8*)&sB[0][wc * 4 + i][lane * 8];
      bl[i] = *(const f16x8*)&sB[1][wc * 4 + i][lane * 8];
    }
#pragma unroll
    for (int i = 0; i < 4; ++i)
#pragma unroll
      for (int j = 0; j < 4; ++j) {
        accH[i][j] = __builtin_amdgcn_mfma_f32_16x16x32_f16(ah[i], bh[j], accH[i][j], 0, 0, 0);
        accX[i][j] = __builtin_amdgcn_mfma_f32_16x16x32_f16(al[i], bh[j], accX[i][j], 0, 0, 0);
        accX[i][j] = __builtin_amdgcn_mfma_f32_16x16x32_f16(ah[i], bl[j], accX[i][j], 0, 0, 0);
      }
  }

  // epilogue: C = accH + accX * 2^-11   (C/D: col = l&15, row = (l>>4)*4 + r)
#pragma unroll
  for (int i = 0; i < 4; ++i) {
    const int row0 = blockIdx.y * 128 + wr * 64 + i * 16 + lg * 4;
    const int col0 = coff + blockIdx.x * 128 + wc * 64 + lr;
#pragma unroll
    for (int r = 0; r < 4; ++r) {
      float* cp = C + (size_t)(row0 + r) * ldC + col0;
#pragma unroll
      for (int j = 0; j < 4; ++j)
        cp[j * 16] = accH[i][j][r] + accX[i][j][r] * 4.8828125e-4f;
    }
  }
}

// ---------------- in-place RoPE (unchanged) ---------------------------------
__global__ __launch_bounds__(256) void rope_inplace(float* __restrict__ qkv,
                                                    const int* __restrict__ pos) {
  int idx = blockIdx.x * 256 + threadIdx.x;
  int j = idx & 63;
  int h = (idx >> 6) & 15;
  int s = (idx >> 10) & (SEQ - 1);
  int b = idx >> 21;
  float p = (float)pos[b * SEQ + s];
  float inv = (float)exp(-(double)j * 1.4391156831212787e-1);
  float ang = p * inv;
  float sn = sinf(ang);
  float cs = cosf(ang);
  size_t row = (size_t)(b * SEQ + s) * QKV_N;
  float* qp = qkv + row + h * HDIM;
  float x1 = qp[j], x2 = qp[j + 64];
  qp[j] = x1 * cs - x2 * sn;
  qp[j + 64] = x2 * cs + x1 * sn;
  float* kp = qkv + row + HIDDEN + h * HDIM;
  x1 = kp[j]; x2 = kp[j + 64];
  kp[j] = x1 * cs - x2 * sn;
  kp[j + 64] = x2 * cs + x1 * sn;
}

// ---------------- key_gate (unchanged, f32) ---------------------------------
__global__ __launch_bounds__(128) void key_gate_k(const float* __restrict__ qkv,
                                                  float* __restrict__ kg) {
  int bhn = blockIdx.x;
  int d = threadIdx.x;
  int n = bhn & 7;
  int bh = bhn >> 3;
  int b = bh >> 4, h = bh & 15;
  const float* kp = qkv + (size_t)(b * SEQ + n * CHUNKSZ) * QKV_N + HIDDEN + h * HDIM + d;
  float sum = 0.f;
  for (int i = 0; i < CHUNKSZ; ++i) sum += kp[(size_t)i * QKV_N];
  kg[(size_t)bh * NCHUNK * HDIM + n * HDIM + d] = sum * (1.f / CHUNKSZ);
}

// ---------------- gate + top-k (unchanged, f32 — precision-critical) --------
__global__ __launch_bounds__(256) void gate_topk(const float* __restrict__ qkv,
                                                 const float* __restrict__ kg,
                                                 unsigned char* __restrict__ msk) {
  int gw = (blockIdx.x * 256 + threadIdx.x) >> 6;
  int lane = threadIdx.x & 63;
  int s = gw & (SEQ - 1);
  int bh = gw >> 11;
  int b = bh >> 4, h = bh & 15;
  int cq = s >> 8;
  const float* qp = qkv + (size_t)(b * SEQ + s) * QKV_N + h * HDIM;
  float q0 = qp[lane], q1 = qp[lane + 64];
  const float* kgp = kg + (size_t)bh * NCHUNK * HDIM;
  float g[7];
#pragma unroll
  for (int n = 0; n < 7; ++n) {
    float part = 0.f;
    if (n < cq) part = q0 * kgp[n * HDIM + lane] + q1 * kgp[n * HDIM + lane + 64];
#pragma unroll
    for (int off = 32; off > 0; off >>= 1) part += __shfl_xor(part, off);
    g[n] = part;
  }
  unsigned m = 1u << cq;
  int nsel = cq < 3 ? cq : 3;
#pragma unroll
  for (int it = 0; it < 3; ++it) {
    int best = -1; float bv = 0.f;
#pragma unroll
    for (int n = 0; n < 7; ++n) {
      bool cand = (n < cq) && !((m >> n) & 1u);
      if (cand && (best < 0 || g[n] > bv)) { bv = g[n]; best = n; }
    }
    if (it < nsel) m |= 1u << best;
  }
  if (lane == 0) msk[gw] = (unsigned char)m;
}

// ---------------- prep: K -> frag-linear bf16 hi/lo (unchanged) -------------
__global__ __launch_bounds__(256) void prep_k(const float* __restrict__ qkv,
                                              u16* __restrict__ khi,
                                              u16* __restrict__ klo) {
  int idx = blockIdx.x * 256 + threadIdx.x;
  int lane = idx & 63;
  int ds = (idx >> 6) & 3;
  int kt = (idx >> 8) & 127;
  int bh = idx >> 15;
  int b = bh >> 4, h = bh & 15;
  int s = kt * 16 + (lane & 15);
  int d = ds * 32 + (lane >> 4) * 8;
  const float* src = qkv + (size_t)(b * SEQ + s) * QKV_N + HIDDEN + h * HDIM + d;
  float4 a = *(const float4*)src;
  float4 c = *(const float4*)(src + 4);
  float xs[8] = {a.x, a.y, a.z, a.w, c.x, c.y, c.z, c.w};
  s16x8 hi, lo;
#pragma unroll
  for (int j = 0; j < 8; ++j) {
    u16 hb = f2bf(xs[j]);
    hi[j] = (short)hb;
    lo[j] = (short)f2bf(xs[j] - bf2f(hb));
  }
  size_t dst = (size_t)idx * 8;
  *(s16x8*)&khi[dst] = hi;
  *(s16x8*)&klo[dst] = lo;
}

// ---------------- prep: V^T -> frag-linear bf16 hi/lo (unchanged) -----------
__global__ __launch_bounds__(256) void prep_v(const float* __restrict__ qkv,
                                              u16* __restrict__ vhi,
                                              u16* __restrict__ vlo) {
  int idx = blockIdx.x * 256 + threadIdx.x;
  int lane = idx & 63;
  int ts = (idx >> 6) & 63;
  int dt = (idx >> 12) & 7;
  int bh = idx >> 15;
  int b = bh >> 4, h = bh & 15;
  int t = ts * 32 + (lane >> 4) * 8;
  int d = dt * 16 + (lane & 15);
  const float* src = qkv + (size_t)(b * SEQ + t) * QKV_N + 2 * HIDDEN + h * HDIM + d;
  s16x8 hi, lo;
#pragma unroll
  for (int j = 0; j < 8; ++j) {
    float x = src[(size_t)j * QKV_N];
    u16 hb = f2bf(x);
    hi[j] = (short)hb;
    lo[j] = (short)f2bf(x - bf2f(hb));
  }
  size_t dst = (size_t)idx * 8;
  *(s16x8*)&vhi[dst] = hi;
  *(s16x8*)&vlo[dst] = lo;
}

// ---------------- MoBA flash attention: split-bf16 MFMA (unchanged) ---------
#define PSTRIDE 40
__global__ __launch_bounds__(256) void moba_attn_mfma(
    const float* __restrict__ qkv,
    const u16* __restrict__ khi, const u16* __restrict__ klo,
    const u16* __restrict__ vhi, const u16* __restrict__ vlo,
    const unsigned char* __restrict__ msk, float* __restrict__ o) {
  __shared__ u16 KHI[4096], KLO[4096];
  __shared__ u16 VHI[4096], VLO[4096];
  __shared__ u16 PHI[4][16 * PSTRIDE], PLO[4][16 * PSTRIDE];
  __shared__ unsigned char Ms[64];
  __shared__ unsigned bm_sh;

  const int qt = blockIdx.x, h = blockIdx.y, b = blockIdx.z;
  const int tid = threadIdx.x;
  const int w = tid >> 6, lane = tid & 63;
  const int lr = lane & 15, lg = lane >> 4;
  const int bh = b * NHEAD + h;
  const int q0g = qt * 64;
  const int q0w = q0g + w * 16;
  const int cq = qt >> 2;

  if (tid < 64) Ms[tid] = msk[(size_t)bh * SEQ + q0g + tid];
  __syncthreads();
  if (tid == 0) {
    unsigned m = 0;
    for (int i = 0; i < 64; ++i) m |= Ms[i];
    bm_sh = m;
  }

  s16x8 qh[4], ql[4];
  {
    const float* qp = qkv + (size_t)(b * SEQ + q0w + lr) * QKV_N + h * HDIM + lg * 8;
#pragma unroll
    for (int ds = 0; ds < 4; ++ds) {
      float4 a = *(const float4*)(qp + ds * 32);
      float4 c = *(const float4*)(qp + ds * 32 + 4);
      float xs[8] = {a.x, a.y, a.z, a.w, c.x, c.y, c.z, c.w};
      s16x8 hi, lo;
#pragma unroll
      for (int j = 0; j < 8; ++j) {
        u16 hb = f2bf(xs[j]);
        hi[j] = (short)hb;
        lo[j] = (short)f2bf(xs[j] - bf2f(hb));
      }
      qh[ds] = hi; ql[ds] = lo;
    }
  }
  __syncthreads();
  const unsigned bmask = bm_sh;

  int qrow[4]; unsigned char rowm[4];
#pragma unroll
  for (int r = 0; r < 4; ++r) {
    qrow[r] = q0w + lg * 4 + r;
    rowm[r] = Ms[w * 16 + lg * 4 + r];
  }

  float m_run[4], l_run[4];
  f32x4 Oacc[8];
#pragma unroll
  for (int r = 0; r < 4; ++r) { m_run[r] = NEGBIG; l_run[r] = 0.f; }
#pragma unroll
  for (int dt = 0; dt < 8; ++dt) Oacc[dt] = (f32x4){0.f, 0.f, 0.f, 0.f};

  for (int n = 0; n <= cq; ++n) {
    if (!((bmask >> n) & 1u)) continue;
    const int nk = (n == cq) ? ((qt & 3) * 64 + 64) : CHUNKSZ;
    for (int t0 = n * CHUNKSZ; t0 < n * CHUNKSZ + nk; t0 += 32) {
      __syncthreads();
      if (w < 2) {
        const u16* src = (w == 0 ? khi : klo) +
                         ((size_t)bh * 128 + (t0 >> 4)) * 2048 + lane * 8;
        u16* dst = (w == 0 ? KHI : KLO);
#pragma unroll
        for (int i = 0; i < 8; ++i)
          *(s16x8*)&dst[i * 512 + lane * 8] = *(const s16x8*)(src + i * 512);
      } else {
        const u16* src = (w == 2 ? vhi : vlo) +
                         ((size_t)bh * 8 * 64 + (t0 >> 5)) * 512 + lane * 8;
        u16* dst = (w == 2 ? VHI : VLO);
#pragma unroll
        for (int dt = 0; dt < 8; ++dt)
          *(s16x8*)&dst[dt * 512 + lane * 8] = *(const s16x8*)(src + (size_t)dt * 32768);
      }
      __syncthreads();

      f32x4 acc[2];
      acc[0] = (f32x4){0.f, 0.f, 0.f, 0.f};
      acc[1] = (f32x4){0.f, 0.f, 0.f, 0.f};
#pragma unroll
      for (int kt = 0; kt < 2; ++kt)
#pragma unroll
        for (int ds = 0; ds < 4; ++ds) {
          s16x8 bhf = *(const s16x8*)&KHI[(kt * 4 + ds) * 512 + lane * 8];
          s16x8 blf = *(const s16x8*)&KLO[(kt * 4 + ds) * 512 + lane * 8];
          acc[kt] = __builtin_amdgcn_mfma_f32_16x16x32_bf16(qh[ds], bhf, acc[kt], 0, 0, 0);
          acc[kt] = __builtin_amdgcn_mfma_f32_16x16x32_bf16(ql[ds], bhf, acc[kt], 0, 0, 0);
          acc[kt] = __builtin_amdgcn_mfma_f32_16x16x32_bf16(qh[ds], blf, acc[kt], 0, 0, 0);
        }

      const int tg0 = t0 + lr, tg1 = t0 + 16 + lr;
      float alpha[4], p0v[4], p1v[4];
#pragma unroll
      for (int r = 0; r < 4; ++r) {
        bool okm = (rowm[r] >> n) & 1;
        float a0 = (okm && tg0 <= qrow[r]) ? acc[0][r] * SCALE_F : NEGBIG;
        float a1 = (okm && tg1 <= qrow[r]) ? acc[1][r] * SCALE_F : NEGBIG;
        float mx = fmaxf(a0, a1);
        mx = fmaxf(mx, __shfl_xor(mx, 1));
        mx = fmaxf(mx, __shfl_xor(mx, 2));
        mx = fmaxf(mx, __shfl_xor(mx, 4));
        mx = fmaxf(mx, __shfl_xor(mx, 8));
        float mnew = fmaxf(m_run[r], mx);
        float al = __expf(m_run[r] - mnew);
        float p0 = __expf(a0 - mnew);
        float p1 = __expf(a1 - mnew);
        float ps = p0 + p1;
        ps += __shfl_xor(ps, 1);
        ps += __shfl_xor(ps, 2);
        ps += __shfl_xor(ps, 4);
        ps += __shfl_xor(ps, 8);
        l_run[r] = l_run[r] * al + ps;
        m_run[r] = mnew;
        alpha[r] = al; p0v[r] = p0; p1v[r] = p1;
      }
      f32x4 av = {alpha[0], alpha[1], alpha[2], alpha[3]};
#pragma unroll
      for (int dt = 0; dt < 8; ++dt) Oacc[dt] *= av;

#pragma unroll
      for (int r = 0; r < 4; ++r) {
        int row = lg * 4 + r;
        u16 h0 = f2bf(p0v[r]);
        u16 h1 = f2bf(p1v[r]);
        PHI[w][row * PSTRIDE + lr]      = h0;
        PHI[w][row * PSTRIDE + 16 + lr] = h1;
        PLO[w][row * PSTRIDE + lr]      = f2bf(p0v[r] - bf2f(h0));
        PLO[w][row * PSTRIDE + 16 + lr] = f2bf(p1v[r] - bf2f(h1));
      }
      s16x8 pah = *(const s16x8*)&PHI[w][lr * PSTRIDE + lg * 8];
      s16x8 pal = *(const s16x8*)&PLO[w][lr * PSTRIDE + lg * 8];
#pragma unroll
      for (int dt = 0; dt < 8; ++dt) {
        s16x8 vbh = *(const s16x8*)&VHI[dt * 512 + lane * 8];
        s16x8 vbl = *(const s16x8*)&VLO[dt * 512 + lane * 8];
        Oacc[dt] = __builtin_amdgcn_mfma_f32_16x16x32_bf16(pah, vbh, Oacc[dt], 0, 0, 0);
        Oacc[dt] = __builtin_amdgcn_mfma_f32_16x16x32_bf16(pal, vbh, Oacc[dt], 0, 0, 0);
        Oacc[dt] = __builtin_amdgcn_mfma_f32_16x16x32_bf16(pah, vbl, Oacc[dt], 0, 0, 0);
      }
    }
  }

  float inv[4];
#pragma unroll
  for (int r = 0; r < 4; ++r) inv[r] = 1.f / l_run[r];
#pragma unroll
  for (int dt = 0; dt < 8; ++dt)
#pragma unroll
    for (int r = 0; r < 4; ++r)
      o[(size_t)(b * SEQ + qrow[r]) * HIDDEN + h * HDIM + dt * 16 + lr] =
          Oacc[dt][r] * inv[r];
}

// ---------------------------------------------------------------------------
extern "C" void kernel_launch(void* const* d_in, const int* in_sizes, int n_in,
                              void* d_out, int out_size, void* d_ws, size_t ws_size,
                              hipStream_t stream) {
  const float* hs    = (const float*)d_in[0];
  const int*   pos   = (const int*)d_in[1];
  const float* w_qkv = (const float*)d_in[2];
  const float* w_o   = (const float*)d_in[3];
  float* out = (float*)d_out;

  char* ws = (char*)d_ws;
  float* qkv = (float*)ws;                                  // 100,663,296 B
  float* o   = (float*)(ws + 100663296);                    //  33,554,432 B
  float* kg  = (float*)(ws + 134217728);                    //     131,072 B
  unsigned char* msk = (unsigned char*)(ws + 134348800);    //      65,536 B
  char* rx   = ws + 134414336;                              //  67,108,864 B arena
  // GEMM phases: fraglin fp16 buffers
  f16* Ah = (f16*)rx;
  f16* Al = (f16*)(rx + 16777216);
  f16* Bh = (f16*)(rx + 33554432);
  f16* Bl = (f16*)(rx + 41943040);
  // KV phase (after GEMM1, arena reused)
  u16* khi = (u16*)rx;
  u16* klo = (u16*)(rx + 16777216);
  u16* vhi = (u16*)(rx + 33554432);
  u16* vlo = (u16*)(rx + 50331648);

  // 1) QKV projection via split-fp16 MFMA, 3 N-slices of 2048
  prep_fl<<<4096, 256, 0, stream>>>(hs, Ah, Al);
  for (int i = 0; i < 3; ++i) {
    prep_fl<<<2048, 256, 0, stream>>>(w_qkv + (size_t)i * 2048 * 2048, Bh, Bl);
    gemm_fl<<<dim3(16, 32), 256, 0, stream>>>(Ah, Al, Bh, Bl, qkv, QKV_N, i * 2048);
  }
  // 2) RoPE in place
  rope_inplace<<<16384, 256, 0, stream>>>(qkv, pos);
  // 3) chunk key means (f32)
  key_gate_k<<<2 * NHEAD * NCHUNK, 128, 0, stream>>>(qkv, kg);
  // 4) gate + top-k mask (f32)
  gate_topk<<<16384, 256, 0, stream>>>(qkv, kg, msk);
  // 5) K/V -> frag-linear bf16 hi/lo (arena reuse: GEMM1 fraglin is dead)
  prep_k<<<4096, 256, 0, stream>>>(qkv, khi, klo);
  prep_v<<<4096, 256, 0, stream>>>(qkv, vhi, vlo);
  // 6) MFMA attention
  moba_attn_mfma<<<dim3(SEQ / 64, NHEAD, 2), 256, 0, stream>>>(qkv, khi, klo,
                                                               vhi, vlo, msk, o);
  // 7) output projection via split-fp16 MFMA (arena reuse: KV dead)
  prep_fl<<<4096, 256, 0, stream>>>(o, Ah, Al);
  prep_fl<<<2048, 256, 0, stream>>>(w_o, Bh, Bl);
  gemm_fl<<<dim3(16, 32), 256, 0, stream>>>(Ah, Al, Bh, Bl, out, HIDDEN, 0);
}

// Round 7
// 882.323 us; speedup vs baseline: 4.7262x; 1.1024x over previous
//
#include <hip/hip_runtime.h>
#include <hip/hip_bf16.h>
#include <math.h>
#include <string.h>

#define SEQ     2048
#define NHEAD   16
#define HDIM    128
#define HIDDEN  2048
#define QKV_N   6144
#define CHUNKSZ 256
#define NCHUNK  8
#define SCALE_F 0.08838834764831845f
#define NEGBIG  -1e30f

typedef unsigned short u16;
typedef unsigned int   u32;
typedef _Float16       f16;
typedef __attribute__((ext_vector_type(8))) short    s16x8;
typedef __attribute__((ext_vector_type(8))) _Float16 f16x8;
typedef __attribute__((ext_vector_type(4))) float    f32x4;

__device__ __forceinline__ u16 f2bf(float x) {
  __hip_bfloat16 h = __float2bfloat16(x);
  u16 r; memcpy(&r, &h, 2); return r;
}
__device__ __forceinline__ float bf2f(u16 u) {
  u32 b = (u32)u << 16; float f; memcpy(&f, &b, 4); return f;
}

// ---------------- prep: f32 row-major [R][2048] -> frag-linear fp16 hi/lo ---
__global__ __launch_bounds__(256) void prep_fl(const float* __restrict__ src,
                                               f16* __restrict__ hi,
                                               f16* __restrict__ lo) {
  int idx = blockIdx.x * 256 + threadIdx.x;
  int l  = idx & 63;
  int ks = (idx >> 6) & 63;
  int mt = idx >> 12;
  const float* sp = src + (size_t)(mt * 16 + (l & 15)) * 2048 + ks * 32 + (l >> 4) * 8;
  float4 a = *(const float4*)sp;
  float4 b = *(const float4*)(sp + 4);
  float xs[8] = {a.x, a.y, a.z, a.w, b.x, b.y, b.z, b.w};
  f16x8 hv, lv;
#pragma unroll
  for (int j = 0; j < 8; ++j) {
    _Float16 h = (_Float16)xs[j];
    hv[j] = h;
    lv[j] = (_Float16)((xs[j] - (float)h) * 2048.0f);
  }
  size_t d = (size_t)idx * 8;
  *(f16x8*)&hi[d] = hv;
  *(f16x8*)&lo[d] = lv;
}

// ---------------- split-fp16 MFMA GEMM (unchanged from round 6) -------------
__global__ __launch_bounds__(256, 2) void gemm_fl(
    const f16* __restrict__ Ah, const f16* __restrict__ Al,
    const f16* __restrict__ Bh, const f16* __restrict__ Bl,
    float* __restrict__ C, int ldC, int coff) {
  __shared__ __align__(16) f16 sA[2][8][512];
  __shared__ __align__(16) f16 sB[2][8][512];
  const int tid = threadIdx.x;
  const int w = tid >> 6, lane = tid & 63;
  const int wr = w >> 1, wc = w & 1;
  const int lr = lane & 15, lg = lane >> 4;
  const int bm8 = blockIdx.y * 8;
  const int bn8 = blockIdx.x * 8;

  const f16* gmat = (w == 0) ? Ah : (w == 1) ? Al : (w == 2) ? Bh : Bl;
  const int  base8 = (w < 2) ? bm8 : bn8;
  f16* lmat = (w == 0) ? &sA[0][0][0] : (w == 1) ? &sA[1][0][0]
            : (w == 2) ? &sB[0][0][0] : &sB[1][0][0];
  const f16* gw = gmat + (size_t)lane * 8;
  f16* lw = lmat + lane * 8;

  f32x4 accH[4][4], accX[4][4];
#pragma unroll
  for (int i = 0; i < 4; ++i)
#pragma unroll
    for (int j = 0; j < 4; ++j) {
      accH[i][j] = (f32x4){0.f, 0.f, 0.f, 0.f};
      accX[i][j] = (f32x4){0.f, 0.f, 0.f, 0.f};
    }

  for (int ks = 0; ks < 64; ++ks) {
    f16x8 stg[8];
#pragma unroll
    for (int i = 0; i < 8; ++i)
      stg[i] = *(const f16x8*)(gw + (((size_t)(base8 + i) * 64 + ks) << 9));
    __syncthreads();
#pragma unroll
    for (int i = 0; i < 8; ++i)
      *(f16x8*)(lw + (i << 9)) = stg[i];
    __syncthreads();

    f16x8 ah[4], al[4], bh[4], bl[4];
#pragma unroll
    for (int i = 0; i < 4; ++i) {
      ah[i] = *(const f16x8*)&sA[0][wr * 4 + i][lane * 8];
      al[i] = *(const f16x8*)&sA[1][wr * 4 + i][lane * 8];
      bh[i] = *(const f16x8*)&sB[0][wc * 4 + i][lane * 8];
      bl[i] = *(const f16x8*)&sB[1][wc * 4 + i][lane * 8];
    }
#pragma unroll
    for (int i = 0; i < 4; ++i)
#pragma unroll
      for (int j = 0; j < 4; ++j) {
        accH[i][j] = __builtin_amdgcn_mfma_f32_16x16x32_f16(ah[i], bh[j], accH[i][j], 0, 0, 0);
        accX[i][j] = __builtin_amdgcn_mfma_f32_16x16x32_f16(al[i], bh[j], accX[i][j], 0, 0, 0);
        accX[i][j] = __builtin_amdgcn_mfma_f32_16x16x32_f16(ah[i], bl[j], accX[i][j], 0, 0, 0);
      }
  }

#pragma unroll
  for (int i = 0; i < 4; ++i) {
    const int row0 = blockIdx.y * 128 + wr * 64 + i * 16 + lg * 4;
    const int col0 = coff + blockIdx.x * 128 + wc * 64 + lr;
#pragma unroll
    for (int r = 0; r < 4; ++r) {
      float* cp = C + (size_t)(row0 + r) * ldC + col0;
#pragma unroll
      for (int j = 0; j < 4; ++j)
        cp[j * 16] = accH[i][j][r] + accX[i][j][r] * 4.8828125e-4f;
    }
  }
}

// ---------------- in-place RoPE (unchanged) ---------------------------------
__global__ __launch_bounds__(256) void rope_inplace(float* __restrict__ qkv,
                                                    const int* __restrict__ pos) {
  int idx = blockIdx.x * 256 + threadIdx.x;
  int j = idx & 63;
  int h = (idx >> 6) & 15;
  int s = (idx >> 10) & (SEQ - 1);
  int b = idx >> 21;
  float p = (float)pos[b * SEQ + s];
  float inv = (float)exp(-(double)j * 1.4391156831212787e-1);
  float ang = p * inv;
  float sn = sinf(ang);
  float cs = cosf(ang);
  size_t row = (size_t)(b * SEQ + s) * QKV_N;
  float* qp = qkv + row + h * HDIM;
  float x1 = qp[j], x2 = qp[j + 64];
  qp[j] = x1 * cs - x2 * sn;
  qp[j + 64] = x2 * cs + x1 * sn;
  float* kp = qkv + row + HIDDEN + h * HDIM;
  x1 = kp[j]; x2 = kp[j + 64];
  kp[j] = x1 * cs - x2 * sn;
  kp[j + 64] = x2 * cs + x1 * sn;
}

// ---------------- key_gate (unchanged, f32) ---------------------------------
__global__ __launch_bounds__(128) void key_gate_k(const float* __restrict__ qkv,
                                                  float* __restrict__ kg) {
  int bhn = blockIdx.x;
  int d = threadIdx.x;
  int n = bhn & 7;
  int bh = bhn >> 3;
  int b = bh >> 4, h = bh & 15;
  const float* kp = qkv + (size_t)(b * SEQ + n * CHUNKSZ) * QKV_N + HIDDEN + h * HDIM + d;
  float sum = 0.f;
  for (int i = 0; i < CHUNKSZ; ++i) sum += kp[(size_t)i * QKV_N];
  kg[(size_t)bh * NCHUNK * HDIM + n * HDIM + d] = sum * (1.f / CHUNKSZ);
}

// ---------------- gate + top-k (unchanged, f32 — precision-critical) --------
__global__ __launch_bounds__(256) void gate_topk(const float* __restrict__ qkv,
                                                 const float* __restrict__ kg,
                                                 unsigned char* __restrict__ msk) {
  int gw = (blockIdx.x * 256 + threadIdx.x) >> 6;
  int lane = threadIdx.x & 63;
  int s = gw & (SEQ - 1);
  int bh = gw >> 11;
  int b = bh >> 4, h = bh & 15;
  int cq = s >> 8;
  const float* qp = qkv + (size_t)(b * SEQ + s) * QKV_N + h * HDIM;
  float q0 = qp[lane], q1 = qp[lane + 64];
  const float* kgp = kg + (size_t)bh * NCHUNK * HDIM;
  float g[7];
#pragma unroll
  for (int n = 0; n < 7; ++n) {
    float part = 0.f;
    if (n < cq) part = q0 * kgp[n * HDIM + lane] + q1 * kgp[n * HDIM + lane + 64];
#pragma unroll
    for (int off = 32; off > 0; off >>= 1) part += __shfl_xor(part, off);
    g[n] = part;
  }
  unsigned m = 1u << cq;
  int nsel = cq < 3 ? cq : 3;
#pragma unroll
  for (int it = 0; it < 3; ++it) {
    int best = -1; float bv = 0.f;
#pragma unroll
    for (int n = 0; n < 7; ++n) {
      bool cand = (n < cq) && !((m >> n) & 1u);
      if (cand && (best < 0 || g[n] > bv)) { bv = g[n]; best = n; }
    }
    if (it < nsel) m |= 1u << best;
  }
  if (lane == 0) msk[gw] = (unsigned char)m;
}

// ---------------- prep: K -> frag-linear bf16 hi/lo (unchanged) -------------
__global__ __launch_bounds__(256) void prep_k(const float* __restrict__ qkv,
                                              u16* __restrict__ khi,
                                              u16* __restrict__ klo) {
  int idx = blockIdx.x * 256 + threadIdx.x;
  int lane = idx & 63;
  int ds = (idx >> 6) & 3;
  int kt = (idx >> 8) & 127;
  int bh = idx >> 15;
  int b = bh >> 4, h = bh & 15;
  int s = kt * 16 + (lane & 15);
  int d = ds * 32 + (lane >> 4) * 8;
  const float* src = qkv + (size_t)(b * SEQ + s) * QKV_N + HIDDEN + h * HDIM + d;
  float4 a = *(const float4*)src;
  float4 c = *(const float4*)(src + 4);
  float xs[8] = {a.x, a.y, a.z, a.w, c.x, c.y, c.z, c.w};
  s16x8 hi, lo;
#pragma unroll
  for (int j = 0; j < 8; ++j) {
    u16 hb = f2bf(xs[j]);
    hi[j] = (short)hb;
    lo[j] = (short)f2bf(xs[j] - bf2f(hb));
  }
  size_t dst = (size_t)idx * 8;
  *(s16x8*)&khi[dst] = hi;
  *(s16x8*)&klo[dst] = lo;
}

// ---------------- prep: V^T -> frag-linear bf16 hi/lo (unchanged) -----------
__global__ __launch_bounds__(256) void prep_v(const float* __restrict__ qkv,
                                              u16* __restrict__ vhi,
                                              u16* __restrict__ vlo) {
  int idx = blockIdx.x * 256 + threadIdx.x;
  int lane = idx & 63;
  int ts = (idx >> 6) & 63;
  int dt = (idx >> 12) & 7;
  int bh = idx >> 15;
  int b = bh >> 4, h = bh & 15;
  int t = ts * 32 + (lane >> 4) * 8;
  int d = dt * 16 + (lane & 15);
  const float* src = qkv + (size_t)(b * SEQ + t) * QKV_N + 2 * HIDDEN + h * HDIM + d;
  s16x8 hi, lo;
#pragma unroll
  for (int j = 0; j < 8; ++j) {
    float x = src[(size_t)j * QKV_N];
    u16 hb = f2bf(x);
    hi[j] = (short)hb;
    lo[j] = (short)f2bf(x - bf2f(hb));
  }
  size_t dst = (size_t)idx * 8;
  *(s16x8*)&vhi[dst] = hi;
  *(s16x8*)&vlo[dst] = lo;
}

// ---------------- MoBA flash attention: split-bf16 MFMA, v2 -----------------
// Changes vs round 6 (numerics byte-identical):
//  * XCD swizzle: each XCD owns 4 complete (b,h) groups -> K/V L2-resident
//  * heavy-first: qt descending within each (b,h) sequence (tail reduction)
//  * software pipeline: next subtile's global loads issued before compute
//  * s_setprio(1) around MFMA clusters
#define PSTRIDE 40
__global__ __launch_bounds__(256) void moba_attn_mfma(
    const float* __restrict__ qkv,
    const u16* __restrict__ khi, const u16* __restrict__ klo,
    const u16* __restrict__ vhi, const u16* __restrict__ vlo,
    const unsigned char* __restrict__ msk, float* __restrict__ o) {
  __shared__ u16 KHI[4096], KLO[4096];
  __shared__ u16 VHI[4096], VLO[4096];
  __shared__ u16 PHI[4][16 * PSTRIDE], PLO[4][16 * PSTRIDE];
  __shared__ unsigned char Ms[64];
  __shared__ unsigned bm_sh;

  // decode swizzled linear block id: xcd = L%8 stays fixed for all 32 qt of a
  // (b,h) group (assumes round-robin dispatch; perf-only). qt heavy-first.
  const int L = blockIdx.x;                 // 0..1023
  const int xcd = L & 7;
  const int t = L >> 3;
  const int qt = 31 - (t & 31);
  const int g = (t >> 5) * 8 + xcd;         // 0..31
  const int b = g >> 4, h = g & 15;

  const int tid = threadIdx.x;
  const int w = tid >> 6, lane = tid & 63;
  const int lr = lane & 15, lg = lane >> 4;
  const int bh = b * NHEAD + h;
  const int q0g = qt * 64;
  const int q0w = q0g + w * 16;
  const int cq = qt >> 2;
  const int dk = (qt & 3) * 64 + 64;        // diagonal-chunk key count

  if (tid < 64) Ms[tid] = msk[(size_t)bh * SEQ + q0g + tid];
  __syncthreads();
  if (tid == 0) {
    unsigned m = 0;
    for (int i = 0; i < 64; ++i) m |= Ms[i];
    bm_sh = m;
  }

  s16x8 qh[4], ql[4];
  {
    const float* qp = qkv + (size_t)(b * SEQ + q0w + lr) * QKV_N + h * HDIM + lg * 8;
#pragma unroll
    for (int ds = 0; ds < 4; ++ds) {
      float4 a = *(const float4*)(qp + ds * 32);
      float4 c = *(const float4*)(qp + ds * 32 + 4);
      float xs[8] = {a.x, a.y, a.z, a.w, c.x, c.y, c.z, c.w};
      s16x8 hi, lo;
#pragma unroll
      for (int j = 0; j < 8; ++j) {
        u16 hb = f2bf(xs[j]);
        hi[j] = (short)hb;
        lo[j] = (short)f2bf(xs[j] - bf2f(hb));
      }
      qh[ds] = hi; ql[ds] = lo;
    }
  }
  __syncthreads();
  const unsigned bmask = bm_sh;

  int qrow[4]; unsigned char rowm[4];
#pragma unroll
  for (int r = 0; r < 4; ++r) {
    qrow[r] = q0w + lg * 4 + r;
    rowm[r] = Ms[w * 16 + lg * 4 + r];
  }

  float m_run[4], l_run[4];
  f32x4 Oacc[8];
#pragma unroll
  for (int r = 0; r < 4; ++r) { m_run[r] = NEGBIG; l_run[r] = 0.f; }
#pragma unroll
  for (int dt = 0; dt < 8; ++dt) Oacc[dt] = (f32x4){0.f, 0.f, 0.f, 0.f};

  // per-wave staging role (w0:KHI w1:KLO w2:VHI w3:VLO)
  u16* ldst = (w == 0) ? KHI : (w == 1) ? KLO : (w == 2) ? VHI : VLO;

  // ---- software-pipelined K/V-subtile loop (all control block-uniform) ----
  int n = 0;
  while (!((bmask >> n) & 1u)) ++n;         // first selected chunk
  int kt = 0;
  s16x8 stg[8];
  { // prologue load
    const int t0 = n * CHUNKSZ + kt;
    if (w < 2) {
      const u16* src = (w == 0 ? khi : klo) + ((size_t)bh * 128 + (t0 >> 4)) * 2048 + lane * 8;
#pragma unroll
      for (int i = 0; i < 8; ++i) stg[i] = *(const s16x8*)(src + i * 512);
    } else {
      const u16* src = (w == 2 ? vhi : vlo) + ((size_t)bh * 8 * 64 + (t0 >> 5)) * 512 + lane * 8;
#pragma unroll
      for (int i = 0; i < 8; ++i) stg[i] = *(const s16x8*)(src + (size_t)i * 32768);
    }
  }

  for (;;) {
    __syncthreads();                        // prior compute done reading LDS
#pragma unroll
    for (int i = 0; i < 8; ++i)
      *(s16x8*)&ldst[i * 512 + lane * 8] = stg[i];
    __syncthreads();                        // LDS ready

    // advance + prefetch next subtile (overlaps with compute below)
    int n2 = n, kt2 = kt + 32;
    const int nk = (n == cq) ? dk : CHUNKSZ;
    if (kt2 >= nk) {
      n2 = -1; kt2 = 0;
      for (int m = n + 1; m <= cq; ++m)
        if ((bmask >> m) & 1u) { n2 = m; break; }
    }
    if (n2 >= 0) {
      const int t0n = n2 * CHUNKSZ + kt2;
      if (w < 2) {
        const u16* src = (w == 0 ? khi : klo) + ((size_t)bh * 128 + (t0n >> 4)) * 2048 + lane * 8;
#pragma unroll
        for (int i = 0; i < 8; ++i) stg[i] = *(const s16x8*)(src + i * 512);
      } else {
        const u16* src = (w == 2 ? vhi : vlo) + ((size_t)bh * 8 * 64 + (t0n >> 5)) * 512 + lane * 8;
#pragma unroll
        for (int i = 0; i < 8; ++i) stg[i] = *(const s16x8*)(src + (size_t)i * 32768);
      }
    }

    const int t0 = n * CHUNKSZ + kt;

    // ---- QK^T: 16 q x 32 keys, split-bf16 ----
    f32x4 acc[2];
    acc[0] = (f32x4){0.f, 0.f, 0.f, 0.f};
    acc[1] = (f32x4){0.f, 0.f, 0.f, 0.f};
    __builtin_amdgcn_s_setprio(1);
#pragma unroll
    for (int ktt = 0; ktt < 2; ++ktt)
#pragma unroll
      for (int ds = 0; ds < 4; ++ds) {
        s16x8 bhf = *(const s16x8*)&KHI[(ktt * 4 + ds) * 512 + lane * 8];
        s16x8 blf = *(const s16x8*)&KLO[(ktt * 4 + ds) * 512 + lane * 8];
        acc[ktt] = __builtin_amdgcn_mfma_f32_16x16x32_bf16(qh[ds], bhf, acc[ktt], 0, 0, 0);
        acc[ktt] = __builtin_amdgcn_mfma_f32_16x16x32_bf16(ql[ds], bhf, acc[ktt], 0, 0, 0);
        acc[ktt] = __builtin_amdgcn_mfma_f32_16x16x32_bf16(qh[ds], blf, acc[ktt], 0, 0, 0);
      }
    __builtin_amdgcn_s_setprio(0);

    // ---- online softmax over these 32 keys ----
    const int tg0 = t0 + lr, tg1 = t0 + 16 + lr;
    float alpha[4], p0v[4], p1v[4];
#pragma unroll
    for (int r = 0; r < 4; ++r) {
      bool okm = (rowm[r] >> n) & 1;
      float a0 = (okm && tg0 <= qrow[r]) ? acc[0][r] * SCALE_F : NEGBIG;
      float a1 = (okm && tg1 <= qrow[r]) ? acc[1][r] * SCALE_F : NEGBIG;
      float mx = fmaxf(a0, a1);
      mx = fmaxf(mx, __shfl_xor(mx, 1));
      mx = fmaxf(mx, __shfl_xor(mx, 2));
      mx = fmaxf(mx, __shfl_xor(mx, 4));
      mx = fmaxf(mx, __shfl_xor(mx, 8));
      float mnew = fmaxf(m_run[r], mx);
      float al = __expf(m_run[r] - mnew);
      float p0 = __expf(a0 - mnew);
      float p1 = __expf(a1 - mnew);
      float ps = p0 + p1;
      ps += __shfl_xor(ps, 1);
      ps += __shfl_xor(ps, 2);
      ps += __shfl_xor(ps, 4);
      ps += __shfl_xor(ps, 8);
      l_run[r] = l_run[r] * al + ps;
      m_run[r] = mnew;
      alpha[r] = al; p0v[r] = p0; p1v[r] = p1;
    }
    f32x4 av = {alpha[0], alpha[1], alpha[2], alpha[3]};
#pragma unroll
    for (int dt = 0; dt < 8; ++dt) Oacc[dt] *= av;

    // ---- P -> wave-private LDS slab (hi/lo), then PV ----
#pragma unroll
    for (int r = 0; r < 4; ++r) {
      int row = lg * 4 + r;
      u16 h0 = f2bf(p0v[r]);
      u16 h1 = f2bf(p1v[r]);
      PHI[w][row * PSTRIDE + lr]      = h0;
      PHI[w][row * PSTRIDE + 16 + lr] = h1;
      PLO[w][row * PSTRIDE + lr]      = f2bf(p0v[r] - bf2f(h0));
      PLO[w][row * PSTRIDE + 16 + lr] = f2bf(p1v[r] - bf2f(h1));
    }
    s16x8 pah = *(const s16x8*)&PHI[w][lr * PSTRIDE + lg * 8];
    s16x8 pal = *(const s16x8*)&PLO[w][lr * PSTRIDE + lg * 8];
    __builtin_amdgcn_s_setprio(1);
#pragma unroll
    for (int dt = 0; dt < 8; ++dt) {
      s16x8 vbh = *(const s16x8*)&VHI[dt * 512 + lane * 8];
      s16x8 vbl = *(const s16x8*)&VLO[dt * 512 + lane * 8];
      Oacc[dt] = __builtin_amdgcn_mfma_f32_16x16x32_bf16(pah, vbh, Oacc[dt], 0, 0, 0);
      Oacc[dt] = __builtin_amdgcn_mfma_f32_16x16x32_bf16(pal, vbh, Oacc[dt], 0, 0, 0);
      Oacc[dt] = __builtin_amdgcn_mfma_f32_16x16x32_bf16(pah, vbl, Oacc[dt], 0, 0, 0);
    }
    __builtin_amdgcn_s_setprio(0);

    if (n2 < 0) break;
    n = n2; kt = kt2;
  }

  float inv[4];
#pragma unroll
  for (int r = 0; r < 4; ++r) inv[r] = 1.f / l_run[r];
#pragma unroll
  for (int dt = 0; dt < 8; ++dt)
#pragma unroll
    for (int r = 0; r < 4; ++r)
      o[(size_t)(b * SEQ + qrow[r]) * HIDDEN + h * HDIM + dt * 16 + lr] =
          Oacc[dt][r] * inv[r];
}

// ---------------------------------------------------------------------------
extern "C" void kernel_launch(void* const* d_in, const int* in_sizes, int n_in,
                              void* d_out, int out_size, void* d_ws, size_t ws_size,
                              hipStream_t stream) {
  const float* hs    = (const float*)d_in[0];
  const int*   pos   = (const int*)d_in[1];
  const float* w_qkv = (const float*)d_in[2];
  const float* w_o   = (const float*)d_in[3];
  float* out = (float*)d_out;

  char* ws = (char*)d_ws;
  float* qkv = (float*)ws;                                  // 100,663,296 B
  float* o   = (float*)(ws + 100663296);                    //  33,554,432 B
  float* kg  = (float*)(ws + 134217728);                    //     131,072 B
  unsigned char* msk = (unsigned char*)(ws + 134348800);    //      65,536 B
  char* rx   = ws + 134414336;                              //  67,108,864 B arena
  // GEMM phases: fraglin fp16 buffers
  f16* Ah = (f16*)rx;
  f16* Al = (f16*)(rx + 16777216);
  f16* Bh = (f16*)(rx + 33554432);
  f16* Bl = (f16*)(rx + 41943040);
  // KV phase (after GEMM1, arena reused)
  u16* khi = (u16*)rx;
  u16* klo = (u16*)(rx + 16777216);
  u16* vhi = (u16*)(rx + 33554432);
  u16* vlo = (u16*)(rx + 50331648);

  // 1) QKV projection via split-fp16 MFMA, 3 N-slices of 2048
  prep_fl<<<4096, 256, 0, stream>>>(hs, Ah, Al);
  for (int i = 0; i < 3; ++i) {
    prep_fl<<<2048, 256, 0, stream>>>(w_qkv + (size_t)i * 2048 * 2048, Bh, Bl);
    gemm_fl<<<dim3(16, 32), 256, 0, stream>>>(Ah, Al, Bh, Bl, qkv, QKV_N, i * 2048);
  }
  // 2) RoPE in place
  rope_inplace<<<16384, 256, 0, stream>>>(qkv, pos);
  // 3) chunk key means (f32)
  key_gate_k<<<2 * NHEAD * NCHUNK, 128, 0, stream>>>(qkv, kg);
  // 4) gate + top-k mask (f32)
  gate_topk<<<16384, 256, 0, stream>>>(qkv, kg, msk);
  // 5) K/V -> frag-linear bf16 hi/lo (arena reuse: GEMM1 fraglin is dead)
  prep_k<<<4096, 256, 0, stream>>>(qkv, khi, klo);
  prep_v<<<4096, 256, 0, stream>>>(qkv, vhi, vlo);
  // 6) MFMA attention (1D swizzled grid)
  moba_attn_mfma<<<dim3(1024), 256, 0, stream>>>(qkv, khi, klo,
                                                 vhi, vlo, msk, o);
  // 7) output projection via split-fp16 MFMA (arena reuse: KV dead)
  prep_fl<<<4096, 256, 0, stream>>>(o, Ah, Al);
  prep_fl<<<2048, 256, 0, stream>>>(w_o, Bh, Bl);
  gemm_fl<<<dim3(16, 32), 256, 0, stream>>>(Ah, Al, Bh, Bl, out, HIDDEN, 0);
}

// Round 8
// 877.016 us; speedup vs baseline: 4.7548x; 1.0061x over previous
//
#include <hip/hip_runtime.h>
#include <hip/hip_bf16.h>
#include <math.h>
#include <string.h>

#define SEQ     2048
#define NHEAD   16
#define HDIM    128
#define HIDDEN  2048
#define QKV_N   6144
#define CHUNKSZ 256
#define NCHUNK  8
#define SCALE_F 0.08838834764831845f
#define NEGBIG  -1e30f

typedef unsigned short u16;
typedef unsigned int   u32;
typedef _Float16       f16;
typedef __attribute__((ext_vector_type(8))) short    s16x8;
typedef __attribute__((ext_vector_type(8))) _Float16 f16x8;
typedef __attribute__((ext_vector_type(4))) float    f32x4;

__device__ __forceinline__ u16 f2bf(float x) {
  __hip_bfloat16 h = __float2bfloat16(x);
  u16 r; memcpy(&r, &h, 2); return r;
}
__device__ __forceinline__ float bf2f(u16 u) {
  u32 b = (u32)u << 16; float f; memcpy(&f, &b, 4); return f;
}

// ---------------- prep: f32 row-major [R][2048] -> frag-linear fp16 hi/lo ---
__global__ __launch_bounds__(256) void prep_fl(const float* __restrict__ src,
                                               f16* __restrict__ hi,
                                               f16* __restrict__ lo) {
  int idx = blockIdx.x * 256 + threadIdx.x;
  int l  = idx & 63;
  int ks = (idx >> 6) & 63;
  int mt = idx >> 12;
  const float* sp = src + (size_t)(mt * 16 + (l & 15)) * 2048 + ks * 32 + (l >> 4) * 8;
  float4 a = *(const float4*)sp;
  float4 b = *(const float4*)(sp + 4);
  float xs[8] = {a.x, a.y, a.z, a.w, b.x, b.y, b.z, b.w};
  f16x8 hv, lv;
#pragma unroll
  for (int j = 0; j < 8; ++j) {
    _Float16 h = (_Float16)xs[j];
    hv[j] = h;
    lv[j] = (_Float16)((xs[j] - (float)h) * 2048.0f);
  }
  size_t d = (size_t)idx * 8;
  *(f16x8*)&hi[d] = hv;
  *(f16x8*)&lo[d] = lv;
}

// ---------------- split-fp16 MFMA GEMM, v2: software-pipelined --------------
// Same math/layout as round 7; staging restructured (T14): next K-step's
// global loads issue right after the LDS-ready barrier and complete under
// the MFMA cluster; ds_write lands after the next readers-done barrier.
__global__ __launch_bounds__(256, 2) void gemm_fl(
    const f16* __restrict__ Ah, const f16* __restrict__ Al,
    const f16* __restrict__ Bh, const f16* __restrict__ Bl,
    float* __restrict__ C, int ldC, int coff) {
  __shared__ __align__(16) f16 sA[2][8][512];
  __shared__ __align__(16) f16 sB[2][8][512];
  const int tid = threadIdx.x;
  const int w = tid >> 6, lane = tid & 63;
  const int wr = w >> 1, wc = w & 1;
  const int lr = lane & 15, lg = lane >> 4;
  const int bm8 = blockIdx.y * 8;
  const int bn8 = blockIdx.x * 8;

  const f16* gmat = (w == 0) ? Ah : (w == 1) ? Al : (w == 2) ? Bh : Bl;
  const int  base8 = (w < 2) ? bm8 : bn8;
  f16* lmat = (w == 0) ? &sA[0][0][0] : (w == 1) ? &sA[1][0][0]
            : (w == 2) ? &sB[0][0][0] : &sB[1][0][0];
  const f16* gw = gmat + (size_t)(base8 * 64) * 512 + (size_t)lane * 8;
  f16* lw = lmat + lane * 8;

  f32x4 accH[4][4], accX[4][4];
#pragma unroll
  for (int i = 0; i < 4; ++i)
#pragma unroll
    for (int j = 0; j < 4; ++j) {
      accH[i][j] = (f32x4){0.f, 0.f, 0.f, 0.f};
      accX[i][j] = (f32x4){0.f, 0.f, 0.f, 0.f};
    }

  f16x8 stg[8];
#pragma unroll
  for (int i = 0; i < 8; ++i)                       // prologue: ks = 0
    stg[i] = *(const f16x8*)(gw + ((size_t)i * 64) * 512);

  for (int ks = 0; ks < 64; ++ks) {
    __syncthreads();                                // readers done with LDS
#pragma unroll
    for (int i = 0; i < 8; ++i)
      *(f16x8*)(lw + (i << 9)) = stg[i];
    __syncthreads();                                // LDS ready

    if (ks < 63) {                                  // prefetch ks+1 (in flight
      const f16* gn = gw + (size_t)(ks + 1) * 512;  //  during MFMA below)
#pragma unroll
      for (int i = 0; i < 8; ++i)
        stg[i] = *(const f16x8*)(gn + ((size_t)i * 64) * 512);
    }

    f16x8 ah[4], al[4], bh[4], bl[4];
#pragma unroll
    for (int i = 0; i < 4; ++i) {
      ah[i] = *(const f16x8*)&sA[0][wr * 4 + i][lane * 8];
      al[i] = *(const f16x8*)&sA[1][wr * 4 + i][lane * 8];
      bh[i] = *(const f16x8*)&sB[0][wc * 4 + i][lane * 8];
      bl[i] = *(const f16x8*)&sB[1][wc * 4 + i][lane * 8];
    }
    __builtin_amdgcn_s_setprio(1);
#pragma unroll
    for (int i = 0; i < 4; ++i)
#pragma unroll
      for (int j = 0; j < 4; ++j) {
        accH[i][j] = __builtin_amdgcn_mfma_f32_16x16x32_f16(ah[i], bh[j], accH[i][j], 0, 0, 0);
        accX[i][j] = __builtin_amdgcn_mfma_f32_16x16x32_f16(al[i], bh[j], accX[i][j], 0, 0, 0);
        accX[i][j] = __builtin_amdgcn_mfma_f32_16x16x32_f16(ah[i], bl[j], accX[i][j], 0, 0, 0);
      }
    __builtin_amdgcn_s_setprio(0);
  }

  // epilogue: C = accH + accX * 2^-11   (C/D: col = l&15, row = (l>>4)*4 + r)
#pragma unroll
  for (int i = 0; i < 4; ++i) {
    const int row0 = blockIdx.y * 128 + wr * 64 + i * 16 + lg * 4;
    const int col0 = coff + blockIdx.x * 128 + wc * 64 + lr;
#pragma unroll
    for (int r = 0; r < 4; ++r) {
      float* cp = C + (size_t)(row0 + r) * ldC + col0;
#pragma unroll
      for (int j = 0; j < 4; ++j)
        cp[j * 16] = accH[i][j][r] + accX[i][j][r] * 4.8828125e-4f;
    }
  }
}

// ---------------- in-place RoPE (unchanged) ---------------------------------
__global__ __launch_bounds__(256) void rope_inplace(float* __restrict__ qkv,
                                                    const int* __restrict__ pos) {
  int idx = blockIdx.x * 256 + threadIdx.x;
  int j = idx & 63;
  int h = (idx >> 6) & 15;
  int s = (idx >> 10) & (SEQ - 1);
  int b = idx >> 21;
  float p = (float)pos[b * SEQ + s];
  float inv = (float)exp(-(double)j * 1.4391156831212787e-1);
  float ang = p * inv;
  float sn = sinf(ang);
  float cs = cosf(ang);
  size_t row = (size_t)(b * SEQ + s) * QKV_N;
  float* qp = qkv + row + h * HDIM;
  float x1 = qp[j], x2 = qp[j + 64];
  qp[j] = x1 * cs - x2 * sn;
  qp[j + 64] = x2 * cs + x1 * sn;
  float* kp = qkv + row + HIDDEN + h * HDIM;
  x1 = kp[j]; x2 = kp[j + 64];
  kp[j] = x1 * cs - x2 * sn;
  kp[j + 64] = x2 * cs + x1 * sn;
}

// ---------------- key_gate (unchanged, f32) ---------------------------------
__global__ __launch_bounds__(128) void key_gate_k(const float* __restrict__ qkv,
                                                  float* __restrict__ kg) {
  int bhn = blockIdx.x;
  int d = threadIdx.x;
  int n = bhn & 7;
  int bh = bhn >> 3;
  int b = bh >> 4, h = bh & 15;
  const float* kp = qkv + (size_t)(b * SEQ + n * CHUNKSZ) * QKV_N + HIDDEN + h * HDIM + d;
  float sum = 0.f;
  for (int i = 0; i < CHUNKSZ; ++i) sum += kp[(size_t)i * QKV_N];
  kg[(size_t)bh * NCHUNK * HDIM + n * HDIM + d] = sum * (1.f / CHUNKSZ);
}

// ---------------- gate + top-k (unchanged, f32 — precision-critical) --------
__global__ __launch_bounds__(256) void gate_topk(const float* __restrict__ qkv,
                                                 const float* __restrict__ kg,
                                                 unsigned char* __restrict__ msk) {
  int gw = (blockIdx.x * 256 + threadIdx.x) >> 6;
  int lane = threadIdx.x & 63;
  int s = gw & (SEQ - 1);
  int bh = gw >> 11;
  int b = bh >> 4, h = bh & 15;
  int cq = s >> 8;
  const float* qp = qkv + (size_t)(b * SEQ + s) * QKV_N + h * HDIM;
  float q0 = qp[lane], q1 = qp[lane + 64];
  const float* kgp = kg + (size_t)bh * NCHUNK * HDIM;
  float g[7];
#pragma unroll
  for (int n = 0; n < 7; ++n) {
    float part = 0.f;
    if (n < cq) part = q0 * kgp[n * HDIM + lane] + q1 * kgp[n * HDIM + lane + 64];
#pragma unroll
    for (int off = 32; off > 0; off >>= 1) part += __shfl_xor(part, off);
    g[n] = part;
  }
  unsigned m = 1u << cq;
  int nsel = cq < 3 ? cq : 3;
#pragma unroll
  for (int it = 0; it < 3; ++it) {
    int best = -1; float bv = 0.f;
#pragma unroll
    for (int n = 0; n < 7; ++n) {
      bool cand = (n < cq) && !((m >> n) & 1u);
      if (cand && (best < 0 || g[n] > bv)) { bv = g[n]; best = n; }
    }
    if (it < nsel) m |= 1u << best;
  }
  if (lane == 0) msk[gw] = (unsigned char)m;
}

// ---------------- prep: K -> frag-linear bf16 hi/lo (unchanged) -------------
__global__ __launch_bounds__(256) void prep_k(const float* __restrict__ qkv,
                                              u16* __restrict__ khi,
                                              u16* __restrict__ klo) {
  int idx = blockIdx.x * 256 + threadIdx.x;
  int lane = idx & 63;
  int ds = (idx >> 6) & 3;
  int kt = (idx >> 8) & 127;
  int bh = idx >> 15;
  int b = bh >> 4, h = bh & 15;
  int s = kt * 16 + (lane & 15);
  int d = ds * 32 + (lane >> 4) * 8;
  const float* src = qkv + (size_t)(b * SEQ + s) * QKV_N + HIDDEN + h * HDIM + d;
  float4 a = *(const float4*)src;
  float4 c = *(const float4*)(src + 4);
  float xs[8] = {a.x, a.y, a.z, a.w, c.x, c.y, c.z, c.w};
  s16x8 hi, lo;
#pragma unroll
  for (int j = 0; j < 8; ++j) {
    u16 hb = f2bf(xs[j]);
    hi[j] = (short)hb;
    lo[j] = (short)f2bf(xs[j] - bf2f(hb));
  }
  size_t dst = (size_t)idx * 8;
  *(s16x8*)&khi[dst] = hi;
  *(s16x8*)&klo[dst] = lo;
}

// ---------------- prep: V^T -> frag-linear bf16 hi/lo (unchanged) -----------
__global__ __launch_bounds__(256) void prep_v(const float* __restrict__ qkv,
                                              u16* __restrict__ vhi,
                                              u16* __restrict__ vlo) {
  int idx = blockIdx.x * 256 + threadIdx.x;
  int lane = idx & 63;
  int ts = (idx >> 6) & 63;
  int dt = (idx >> 12) & 7;
  int bh = idx >> 15;
  int b = bh >> 4, h = bh & 15;
  int t = ts * 32 + (lane >> 4) * 8;
  int d = dt * 16 + (lane & 15);
  const float* src = qkv + (size_t)(b * SEQ + t) * QKV_N + 2 * HIDDEN + h * HDIM + d;
  s16x8 hi, lo;
#pragma unroll
  for (int j = 0; j < 8; ++j) {
    float x = src[(size_t)j * QKV_N];
    u16 hb = f2bf(x);
    hi[j] = (short)hb;
    lo[j] = (short)f2bf(x - bf2f(hb));
  }
  size_t dst = (size_t)idx * 8;
  *(s16x8*)&vhi[dst] = hi;
  *(s16x8*)&vlo[dst] = lo;
}

// ---------------- MoBA flash attention (unchanged from round 7) -------------
#define PSTRIDE 40
__global__ __launch_bounds__(256) void moba_attn_mfma(
    const float* __restrict__ qkv,
    const u16* __restrict__ khi, const u16* __restrict__ klo,
    const u16* __restrict__ vhi, const u16* __restrict__ vlo,
    const unsigned char* __restrict__ msk, float* __restrict__ o) {
  __shared__ u16 KHI[4096], KLO[4096];
  __shared__ u16 VHI[4096], VLO[4096];
  __shared__ u16 PHI[4][16 * PSTRIDE], PLO[4][16 * PSTRIDE];
  __shared__ unsigned char Ms[64];
  __shared__ unsigned bm_sh;

  const int L = blockIdx.x;                 // 0..1023
  const int xcd = L & 7;
  const int t = L >> 3;
  const int qt = 31 - (t & 31);
  const int g = (t >> 5) * 8 + xcd;         // 0..31
  const int b = g >> 4, h = g & 15;

  const int tid = threadIdx.x;
  const int w = tid >> 6, lane = tid & 63;
  const int lr = lane & 15, lg = lane >> 4;
  const int bh = b * NHEAD + h;
  const int q0g = qt * 64;
  const int q0w = q0g + w * 16;
  const int cq = qt >> 2;
  const int dk = (qt & 3) * 64 + 64;

  if (tid < 64) Ms[tid] = msk[(size_t)bh * SEQ + q0g + tid];
  __syncthreads();
  if (tid == 0) {
    unsigned m = 0;
    for (int i = 0; i < 64; ++i) m |= Ms[i];
    bm_sh = m;
  }

  s16x8 qh[4], ql[4];
  {
    const float* qp = qkv + (size_t)(b * SEQ + q0w + lr) * QKV_N + h * HDIM + lg * 8;
#pragma unroll
    for (int ds = 0; ds < 4; ++ds) {
      float4 a = *(const float4*)(qp + ds * 32);
      float4 c = *(const float4*)(qp + ds * 32 + 4);
      float xs[8] = {a.x, a.y, a.z, a.w, c.x, c.y, c.z, c.w};
      s16x8 hi, lo;
#pragma unroll
      for (int j = 0; j < 8; ++j) {
        u16 hb = f2bf(xs[j]);
        hi[j] = (short)hb;
        lo[j] = (short)f2bf(xs[j] - bf2f(hb));
      }
      qh[ds] = hi; ql[ds] = lo;
    }
  }
  __syncthreads();
  const unsigned bmask = bm_sh;

  int qrow[4]; unsigned char rowm[4];
#pragma unroll
  for (int r = 0; r < 4; ++r) {
    qrow[r] = q0w + lg * 4 + r;
    rowm[r] = Ms[w * 16 + lg * 4 + r];
  }

  float m_run[4], l_run[4];
  f32x4 Oacc[8];
#pragma unroll
  for (int r = 0; r < 4; ++r) { m_run[r] = NEGBIG; l_run[r] = 0.f; }
#pragma unroll
  for (int dt = 0; dt < 8; ++dt) Oacc[dt] = (f32x4){0.f, 0.f, 0.f, 0.f};

  u16* ldst = (w == 0) ? KHI : (w == 1) ? KLO : (w == 2) ? VHI : VLO;

  int n = 0;
  while (!((bmask >> n) & 1u)) ++n;
  int kt = 0;
  s16x8 stg[8];
  {
    const int t0 = n * CHUNKSZ + kt;
    if (w < 2) {
      const u16* src = (w == 0 ? khi : klo) + ((size_t)bh * 128 + (t0 >> 4)) * 2048 + lane * 8;
#pragma unroll
      for (int i = 0; i < 8; ++i) stg[i] = *(const s16x8*)(src + i * 512);
    } else {
      const u16* src = (w == 2 ? vhi : vlo) + ((size_t)bh * 8 * 64 + (t0 >> 5)) * 512 + lane * 8;
#pragma unroll
      for (int i = 0; i < 8; ++i) stg[i] = *(const s16x8*)(src + (size_t)i * 32768);
    }
  }

  for (;;) {
    __syncthreads();
#pragma unroll
    for (int i = 0; i < 8; ++i)
      *(s16x8*)&ldst[i * 512 + lane * 8] = stg[i];
    __syncthreads();

    int n2 = n, kt2 = kt + 32;
    const int nk = (n == cq) ? dk : CHUNKSZ;
    if (kt2 >= nk) {
      n2 = -1; kt2 = 0;
      for (int m = n + 1; m <= cq; ++m)
        if ((bmask >> m) & 1u) { n2 = m; break; }
    }
    if (n2 >= 0) {
      const int t0n = n2 * CHUNKSZ + kt2;
      if (w < 2) {
        const u16* src = (w == 0 ? khi : klo) + ((size_t)bh * 128 + (t0n >> 4)) * 2048 + lane * 8;
#pragma unroll
        for (int i = 0; i < 8; ++i) stg[i] = *(const s16x8*)(src + i * 512);
      } else {
        const u16* src = (w == 2 ? vhi : vlo) + ((size_t)bh * 8 * 64 + (t0n >> 5)) * 512 + lane * 8;
#pragma unroll
        for (int i = 0; i < 8; ++i) stg[i] = *(const s16x8*)(src + (size_t)i * 32768);
      }
    }

    const int t0 = n * CHUNKSZ + kt;

    f32x4 acc[2];
    acc[0] = (f32x4){0.f, 0.f, 0.f, 0.f};
    acc[1] = (f32x4){0.f, 0.f, 0.f, 0.f};
    __builtin_amdgcn_s_setprio(1);
#pragma unroll
    for (int ktt = 0; ktt < 2; ++ktt)
#pragma unroll
      for (int ds = 0; ds < 4; ++ds) {
        s16x8 bhf = *(const s16x8*)&KHI[(ktt * 4 + ds) * 512 + lane * 8];
        s16x8 blf = *(const s16x8*)&KLO[(ktt * 4 + ds) * 512 + lane * 8];
        acc[ktt] = __builtin_amdgcn_mfma_f32_16x16x32_bf16(qh[ds], bhf, acc[ktt], 0, 0, 0);
        acc[ktt] = __builtin_amdgcn_mfma_f32_16x16x32_bf16(ql[ds], bhf, acc[ktt], 0, 0, 0);
        acc[ktt] = __builtin_amdgcn_mfma_f32_16x16x32_bf16(qh[ds], blf, acc[ktt], 0, 0, 0);
      }
    __builtin_amdgcn_s_setprio(0);

    const int tg0 = t0 + lr, tg1 = t0 + 16 + lr;
    float alpha[4], p0v[4], p1v[4];
#pragma unroll
    for (int r = 0; r < 4; ++r) {
      bool okm = (rowm[r] >> n) & 1;
      float a0 = (okm && tg0 <= qrow[r]) ? acc[0][r] * SCALE_F : NEGBIG;
      float a1 = (okm && tg1 <= qrow[r]) ? acc[1][r] * SCALE_F : NEGBIG;
      float mx = fmaxf(a0, a1);
      mx = fmaxf(mx, __shfl_xor(mx, 1));
      mx = fmaxf(mx, __shfl_xor(mx, 2));
      mx = fmaxf(mx, __shfl_xor(mx, 4));
      mx = fmaxf(mx, __shfl_xor(mx, 8));
      float mnew = fmaxf(m_run[r], mx);
      float al = __expf(m_run[r] - mnew);
      float p0 = __expf(a0 - mnew);
      float p1 = __expf(a1 - mnew);
      float ps = p0 + p1;
      ps += __shfl_xor(ps, 1);
      ps += __shfl_xor(ps, 2);
      ps += __shfl_xor(ps, 4);
      ps += __shfl_xor(ps, 8);
      l_run[r] = l_run[r] * al + ps;
      m_run[r] = mnew;
      alpha[r] = al; p0v[r] = p0; p1v[r] = p1;
    }
    f32x4 av = {alpha[0], alpha[1], alpha[2], alpha[3]};
#pragma unroll
    for (int dt = 0; dt < 8; ++dt) Oacc[dt] *= av;

#pragma unroll
    for (int r = 0; r < 4; ++r) {
      int row = lg * 4 + r;
      u16 h0 = f2bf(p0v[r]);
      u16 h1 = f2bf(p1v[r]);
      PHI[w][row * PSTRIDE + lr]      = h0;
      PHI[w][row * PSTRIDE + 16 + lr] = h1;
      PLO[w][row * PSTRIDE + lr]      = f2bf(p0v[r] - bf2f(h0));
      PLO[w][row * PSTRIDE + 16 + lr] = f2bf(p1v[r] - bf2f(h1));
    }
    s16x8 pah = *(const s16x8*)&PHI[w][lr * PSTRIDE + lg * 8];
    s16x8 pal = *(const s16x8*)&PLO[w][lr * PSTRIDE + lg * 8];
    __builtin_amdgcn_s_setprio(1);
#pragma unroll
    for (int dt = 0; dt < 8; ++dt) {
      s16x8 vbh = *(const s16x8*)&VHI[dt * 512 + lane * 8];
      s16x8 vbl = *(const s16x8*)&VLO[dt * 512 + lane * 8];
      Oacc[dt] = __builtin_amdgcn_mfma_f32_16x16x32_bf16(pah, vbh, Oacc[dt], 0, 0, 0);
      Oacc[dt] = __builtin_amdgcn_mfma_f32_16x16x32_bf16(pal, vbh, Oacc[dt], 0, 0, 0);
      Oacc[dt] = __builtin_amdgcn_mfma_f32_16x16x32_bf16(pah, vbl, Oacc[dt], 0, 0, 0);
    }
    __builtin_amdgcn_s_setprio(0);

    if (n2 < 0) break;
    n = n2; kt = kt2;
  }

  float inv[4];
#pragma unroll
  for (int r = 0; r < 4; ++r) inv[r] = 1.f / l_run[r];
#pragma unroll
  for (int dt = 0; dt < 8; ++dt)
#pragma unroll
    for (int r = 0; r < 4; ++r)
      o[(size_t)(b * SEQ + qrow[r]) * HIDDEN + h * HDIM + dt * 16 + lr] =
          Oacc[dt][r] * inv[r];
}

// ---------------------------------------------------------------------------
extern "C" void kernel_launch(void* const* d_in, const int* in_sizes, int n_in,
                              void* d_out, int out_size, void* d_ws, size_t ws_size,
                              hipStream_t stream) {
  const float* hs    = (const float*)d_in[0];
  const int*   pos   = (const int*)d_in[1];
  const float* w_qkv = (const float*)d_in[2];
  const float* w_o   = (const float*)d_in[3];
  float* out = (float*)d_out;

  char* ws = (char*)d_ws;
  float* qkv = (float*)ws;                                  // 100,663,296 B
  float* o   = (float*)(ws + 100663296);                    //  33,554,432 B
  float* kg  = (float*)(ws + 134217728);                    //     131,072 B
  unsigned char* msk = (unsigned char*)(ws + 134348800);    //      65,536 B
  char* rx   = ws + 134414336;                              //  67,108,864 B arena
  // GEMM phases: fraglin fp16 buffers
  f16* Ah = (f16*)rx;
  f16* Al = (f16*)(rx + 16777216);
  f16* Bh = (f16*)(rx + 33554432);
  f16* Bl = (f16*)(rx + 41943040);
  // KV phase (after GEMM1, arena reused)
  u16* khi = (u16*)rx;
  u16* klo = (u16*)(rx + 16777216);
  u16* vhi = (u16*)(rx + 33554432);
  u16* vlo = (u16*)(rx + 50331648);

  // 1) QKV projection via split-fp16 MFMA, 3 N-slices of 2048
  prep_fl<<<4096, 256, 0, stream>>>(hs, Ah, Al);
  for (int i = 0; i < 3; ++i) {
    prep_fl<<<2048, 256, 0, stream>>>(w_qkv + (size_t)i * 2048 * 2048, Bh, Bl);
    gemm_fl<<<dim3(16, 32), 256, 0, stream>>>(Ah, Al, Bh, Bl, qkv, QKV_N, i * 2048);
  }
  // 2) RoPE in place
  rope_inplace<<<16384, 256, 0, stream>>>(qkv, pos);
  // 3) chunk key means (f32)
  key_gate_k<<<2 * NHEAD * NCHUNK, 128, 0, stream>>>(qkv, kg);
  // 4) gate + top-k mask (f32)
  gate_topk<<<16384, 256, 0, stream>>>(qkv, kg, msk);
  // 5) K/V -> frag-linear bf16 hi/lo (arena reuse: GEMM1 fraglin is dead)
  prep_k<<<4096, 256, 0, stream>>>(qkv, khi, klo);
  prep_v<<<4096, 256, 0, stream>>>(qkv, vhi, vlo);
  // 6) MFMA attention (1D swizzled grid)
  moba_attn_mfma<<<dim3(1024), 256, 0, stream>>>(qkv, khi, klo,
                                                 vhi, vlo, msk, o);
  // 7) output projection via split-fp16 MFMA (arena reuse: KV dead)
  prep_fl<<<4096, 256, 0, stream>>>(o, Ah, Al);
  prep_fl<<<2048, 256, 0, stream>>>(w_o, Bh, Bl);
  gemm_fl<<<dim3(16, 32), 256, 0, stream>>>(Ah, Al, Bh, Bl, out, HIDDEN, 0);
}